// Round 1
// baseline (3033.905 us; speedup 1.0000x reference)
//
#include <hip/hip_runtime.h>
#include <cmath>

#define BB 16
#define TT 8192
#define MM (BB*TT)
#define FF 256
#define TBF 5.0f
#define PROJN 29

__device__ __forceinline__ float gelu_exact(float x){
    return 0.5f*x*(1.0f + erff(x*0.70710678118654752440f));
}
__device__ __forceinline__ float softplusf_(float v){
    return fmaxf(v,0.0f) + log1pf(expf(-fabsf(v)));
}
__device__ __forceinline__ float wred(float v){
    #pragma unroll
    for(int o=32;o>0;o>>=1) v += __shfl_xor(v,o,64);
    return v;
}

// h[m][f] = x0[m]*w_pre[f] + b_pre[f]
__global__ __launch_bounds__(256) void pre_kernel(
    const float* __restrict__ x, const float* __restrict__ w_pre,
    const float* __restrict__ b_pre, float* __restrict__ h)
{
    const int idx = blockIdx.x*256 + threadIdx.x;   // float4 index over M*64
    const int m = idx>>6, c = idx&63;
    const float x0 = x[(size_t)m*2];
    const float4 w  = ((const float4*)w_pre)[c];
    const float4 bb = ((const float4*)b_pre)[c];
    float4 o;
    o.x=fmaf(x0,w.x,bb.x); o.y=fmaf(x0,w.y,bb.y);
    o.z=fmaf(x0,w.z,bb.z); o.w=fmaf(x0,w.w,bb.w);
    ((float4*)h)[(size_t)idx] = o;
}

// One layer: y = gelu(LN1(depthwise_dilated_conv(h*mask))) ; z = gelu(LN2(y@w11+b11)) ; hout = hin + z
// Block: 16 rows x 256 cols. 256 threads = 4 waves; wave w owns rows 4w..4w+3.
__global__ __launch_bounds__(256) void layer_kernel(
    const float* __restrict__ hin, float* __restrict__ hout,
    const float* __restrict__ mask,
    const float* __restrict__ dwk, const float* __restrict__ dwb,
    const float* __restrict__ g1, const float* __restrict__ b1,
    const float* __restrict__ w11, const float* __restrict__ b11,
    const float* __restrict__ g2, const float* __restrict__ b2,
    const int dil)
{
    __shared__ float ytile[16][256];
    __shared__ float hctr[16][256];
    __shared__ float wchunk[32*256];

    const int tid = threadIdx.x;
    const int wave = tid>>6, lane = tid&63;
    const int m0 = blockIdx.x*16;          // 16 | 8192 -> tile never crosses batch
    const int b  = m0/TT;
    const int t0 = m0 - b*TT;
    const float* mrow = mask + (size_t)b*TT;

    // ---- Phase 1: conv + LN1 + gelu -> ytile ; stash raw center h -> hctr
    for(int rr=0; rr<4; ++rr){
        const int r = wave*4+rr;
        const int m = m0+r;
        const int t = t0+r;
        float yv[4];
        #pragma unroll
        for(int c=0;c<4;++c){
            const int f = lane + 64*c;
            const float hc = hin[(size_t)m*FF + f];
            hctr[r][f] = hc;
            float acc = fmaf(hc*mrow[t], dwk[FF+f], dwb[f]);      // center tap k=1
            if(t >= dil)    acc = fmaf(hin[(size_t)(m-dil)*FF+f]*mrow[t-dil], dwk[f],       acc);
            if(t+dil < TT)  acc = fmaf(hin[(size_t)(m+dil)*FF+f]*mrow[t+dil], dwk[2*FF+f], acc);
            yv[c]=acc;
        }
        float s = wred(yv[0]+yv[1]+yv[2]+yv[3]);
        const float mean = s*(1.0f/FF);
        float sq=0.0f;
        #pragma unroll
        for(int c=0;c<4;++c){ const float d=yv[c]-mean; sq=fmaf(d,d,sq); }
        sq = wred(sq);
        const float rs = rsqrtf(sq*(1.0f/FF) + 1e-5f);
        #pragma unroll
        for(int c=0;c<4;++c){
            const int f = lane+64*c;
            const float yn = fmaf((yv[c]-mean)*rs, g1[f], b1[f]);
            ytile[r][f] = gelu_exact(yn);
        }
    }

    // ---- Phase 2: GEMM (16x256) @ (256x256), k staged in LDS chunks of 32
    float4 acc[4];
    #pragma unroll
    for(int r4=0;r4<4;++r4) acc[r4]=make_float4(0.f,0.f,0.f,0.f);

    for(int kc=0;kc<8;++kc){
        __syncthreads();   // first iter: ytile/hctr ready; later: wchunk consumed
        #pragma unroll
        for(int it=0; it<8; ++it){
            const int idx = it*256+tid;            // float4 idx within 32x256 chunk
            ((float4*)wchunk)[idx] = ((const float4*)w11)[kc*2048 + idx];
        }
        __syncthreads();
        #pragma unroll
        for(int kk=0;kk<32;++kk){
            const float4 wv = ((const float4*)wchunk)[kk*64 + lane];
            #pragma unroll
            for(int r4=0;r4<4;++r4){
                const float yb = ytile[wave*4+r4][kc*32+kk];
                acc[r4].x=fmaf(yb,wv.x,acc[r4].x);
                acc[r4].y=fmaf(yb,wv.y,acc[r4].y);
                acc[r4].z=fmaf(yb,wv.z,acc[r4].z);
                acc[r4].w=fmaf(yb,wv.w,acc[r4].w);
            }
        }
    }

    // ---- Phase 3: +b11, LN2, gelu, residual, store
    const float4 bv  = ((const float4*)b11)[lane];
    const float4 gv  = ((const float4*)g2)[lane];
    const float4 b2v = ((const float4*)b2)[lane];
    #pragma unroll
    for(int r4=0;r4<4;++r4){
        float4 v = acc[r4];
        v.x+=bv.x; v.y+=bv.y; v.z+=bv.z; v.w+=bv.w;
        const float s = wred(v.x+v.y+v.z+v.w);
        const float mean = s*(1.0f/FF);
        const float d0=v.x-mean, d1=v.y-mean, d2=v.z-mean, d3=v.w-mean;
        const float sq = wred(d0*d0+d1*d1+d2*d2+d3*d3);
        const float rs = rsqrtf(sq*(1.0f/FF)+1e-5f);
        const int r = wave*4+r4;
        const size_t m = (size_t)m0 + r;
        const float4 hc = ((const float4*)&hctr[r][0])[lane];
        float4 o;
        o.x = hc.x + gelu_exact(fmaf(d0*rs, gv.x, b2v.x));
        o.y = hc.y + gelu_exact(fmaf(d1*rs, gv.y, b2v.y));
        o.z = hc.z + gelu_exact(fmaf(d2*rs, gv.z, b2v.z));
        o.w = hc.w + gelu_exact(fmaf(d3*rs, gv.w, b2v.w));
        ((float4*)hout)[m*64 + lane] = o;
    }
}

// P[m][0..28] = ((h[m]*mask) @ w_proj + b_proj) * mask   (P padded to stride 32)
__global__ __launch_bounds__(256) void proj_kernel(
    const float* __restrict__ hin, const float* __restrict__ mask,
    const float* __restrict__ wproj, const float* __restrict__ bproj,
    float* __restrict__ P)
{
    __shared__ float htile[32][260];   // padded: avoid 8-way bank conflict on column reads
    __shared__ float wp[256][32];
    const int tid = threadIdx.x;
    #pragma unroll
    for(int it=0; it<32; ++it){
        const int idx = it*256+tid;
        const int k = idx>>5, c = idx&31;
        wp[k][c] = (c<PROJN)? wproj[k*PROJN+c] : 0.0f;
    }
    const int m0 = blockIdx.x*32;
    #pragma unroll
    for(int it=0; it<8; ++it){
        const int idx = it*256+tid;       // float4 idx within 32x256
        const int r = idx>>6, c4 = idx&63;
        const float mk = mask[m0+r];
        float4 v = ((const float4*)hin)[(size_t)m0*64 + idx];
        v.x*=mk; v.y*=mk; v.z*=mk; v.w*=mk;
        ((float4*)&htile[r][0])[c4] = v;
    }
    __syncthreads();
    const int row = tid>>3, cg = tid&7, c0 = cg*4;
    float4 acc = make_float4(0.f,0.f,0.f,0.f);
    for(int k=0;k<256;++k){
        const float hb = htile[row][k];
        const float4 wv = ((const float4*)&wp[k][0])[cg];
        acc.x=fmaf(hb,wv.x,acc.x);
        acc.y=fmaf(hb,wv.y,acc.y);
        acc.z=fmaf(hb,wv.z,acc.z);
        acc.w=fmaf(hb,wv.w,acc.w);
    }
    const int m = m0+row;
    const float mk = mask[m];
    float4 bp;
    bp.x = bproj[c0];
    bp.y = (c0+1<PROJN)? bproj[c0+1]:0.0f;
    bp.z = (c0+2<PROJN)? bproj[c0+2]:0.0f;
    bp.w = (c0+3<PROJN)? bproj[c0+3]:0.0f;
    float4 o;
    o.x=(acc.x+bp.x)*mk; o.y=(acc.y+bp.y)*mk;
    o.z=(acc.z+bp.z)*mk; o.w=(acc.w+bp.w)*mk;
    ((float4*)P)[(size_t)m*8 + cg] = o;
}

// Rational-quadratic spline per (b,t); writes xo and block-reduced logdet
__global__ __launch_bounds__(256) void spline_kernel(
    const float* __restrict__ P, const float* __restrict__ x,
    const float* __restrict__ mask, float* __restrict__ out,
    float* __restrict__ logdet)
{
    const int tid = threadIdx.x;
    const int m = blockIdx.x*256 + tid;
    float p[32];
    #pragma unroll
    for(int j=0;j<8;++j) ((float4*)p)[j] = ((const float4*)P)[(size_t)m*8+j];
    const float x0 = x[(size_t)m*2];
    const float x1 = x[(size_t)m*2+1];
    const float mk = mask[m];
    const float sc = 0.0625f;           // 1/sqrt(256)

    float cw[11], ch[11], d[11];
    { // widths
        float mx=-1e30f;
        #pragma unroll
        for(int j=0;j<10;++j) mx = fmaxf(mx, p[j]);
        float e[10]; float se=0.f;
        #pragma unroll
        for(int j=0;j<10;++j){ e[j]=expf((p[j]-mx)*sc); se+=e[j]; }
        const float inv = 1.0f/se;
        float cum=0.f;
        cw[0]=-TBF;
        #pragma unroll
        for(int j=0;j<10;++j){ cum += fmaf(0.99f, e[j]*inv, 0.001f); cw[j+1]=fmaf(2.0f*TBF,cum,-TBF); }
        cw[10]=TBF;
    }
    { // heights
        float mx=-1e30f;
        #pragma unroll
        for(int j=0;j<10;++j) mx = fmaxf(mx, p[10+j]);
        float e[10]; float se=0.f;
        #pragma unroll
        for(int j=0;j<10;++j){ e[j]=expf((p[10+j]-mx)*sc); se+=e[j]; }
        const float inv = 1.0f/se;
        float cum=0.f;
        ch[0]=-TBF;
        #pragma unroll
        for(int j=0;j<10;++j){ cum += fmaf(0.99f, e[j]*inv, 0.001f); ch[j+1]=fmaf(2.0f*TBF,cum,-TBF); }
        ch[10]=TBF;
    }
    d[0]=1.0f; d[10]=1.0f;
    #pragma unroll
    for(int k=1;k<10;++k) d[k] = 0.001f + softplusf_(p[19+k]);

    const bool inside = (x1>=-TBF)&&(x1<=TBF);
    const float xc = fminf(fmaxf(x1,-TBF),TBF);

    // bin select: last j with xc >= cw[j], clipped to [0,9] — fully unrolled (registers only)
    float icw=cw[0], ibw=cw[1]-cw[0], ich=ch[0], ibh=ch[1]-ch[0], dk=d[0], dk1=d[1];
    #pragma unroll
    for(int j=1;j<10;++j){
        const bool sel = (xc>=cw[j]);
        icw = sel? cw[j]      : icw;
        ibw = sel? cw[j+1]-cw[j] : ibw;
        ich = sel? ch[j]      : ich;
        ibh = sel? ch[j+1]-ch[j] : ibh;
        dk  = sel? d[j]       : dk;
        dk1 = sel? d[j+1]     : dk1;
    }

    const float delta = ibh/ibw;
    const float th = (xc-icw)/ibw;
    const float th1m = th*(1.0f-th);
    const float denom = fmaf(fmaf(-2.0f,delta,dk+dk1), th1m, delta);
    const float num = ibh*fmaf(delta*th, th, dk*th1m);
    const float yv = ich + num/denom;
    const float omt = 1.0f-th;
    const float dnum = delta*delta*(dk1*th*th + 2.0f*delta*th1m + dk*omt*omt);
    const float lad = logf(dnum) - 2.0f*logf(denom);
    const float y1 = inside? yv : x1;
    const float lv = inside? lad : 0.0f;

    out[(size_t)m*2]   = x0*mk;
    out[(size_t)m*2+1] = y1*mk;

    __shared__ float red[256];
    red[tid]=lv*mk;
    __syncthreads();
    #pragma unroll
    for(int s=128;s>0;s>>=1){ if(tid<s) red[tid]+=red[tid+s]; __syncthreads(); }
    if(tid==0) atomicAdd(&logdet[blockIdx.x>>5], red[0]);  // 32 blocks per batch row
}

extern "C" void kernel_launch(void* const* d_in, const int* in_sizes, int n_in,
                              void* d_out, int out_size, void* d_ws, size_t ws_size,
                              hipStream_t stream)
{
    const float* x      = (const float*)d_in[0];
    const float* mask   = (const float*)d_in[1];
    const float* w_pre  = (const float*)d_in[2];
    const float* b_pre  = (const float*)d_in[3];
    const float* dw_k   = (const float*)d_in[4];
    const float* dw_b   = (const float*)d_in[5];
    const float* w11    = (const float*)d_in[6];
    const float* b11    = (const float*)d_in[7];
    const float* ln1g   = (const float*)d_in[8];
    const float* ln1b   = (const float*)d_in[9];
    const float* ln2g   = (const float*)d_in[10];
    const float* ln2b   = (const float*)d_in[11];
    const float* w_proj = (const float*)d_in[12];
    const float* b_proj = (const float*)d_in[13];

    float* h0 = (float*)d_ws;                       // 128 MiB
    float* h1 = h0 + (size_t)MM*FF;                 // 128 MiB
    float* P  = h0;                                 // overlay (safe: used after layers)
    float* out    = (float*)d_out;
    float* logdet = out + (size_t)MM*2;

    // h0 = x0 * w_pre + b_pre
    pre_kernel<<<MM*64/256, 256, 0, stream>>>(x, w_pre, b_pre, h0);

    // 3 layers, ping-pong h buffers; dil = 1, 3, 9
    const int dils[3] = {1,3,9};
    const float* hi[3] = {h0, h1, h0};
    float*       ho[3] = {h1, h0, h1};
    for(int i=0;i<3;++i){
        layer_kernel<<<MM/16, 256, 0, stream>>>(
            hi[i], ho[i], mask,
            dw_k + (size_t)i*3*FF, dw_b + (size_t)i*FF,
            ln1g + (size_t)i*FF,  ln1b + (size_t)i*FF,
            w11  + (size_t)i*FF*FF, b11 + (size_t)i*FF,
            ln2g + (size_t)i*FF,  ln2b + (size_t)i*FF,
            dils[i]);
    }

    // P = ((h*mask) @ w_proj + b_proj) * mask   (reads h1, writes overlay on h0)
    proj_kernel<<<MM/32, 256, 0, stream>>>(h1, mask, w_proj, b_proj, P);

    // logdet accumulators zeroed, then spline
    hipMemsetAsync(logdet, 0, BB*sizeof(float), stream);
    spline_kernel<<<MM/256, 256, 0, stream>>>(P, x, mask, out, logdet);
}

// Round 4
// 791.382 us; speedup vs baseline: 3.8337x; 3.8337x over previous
//
#include <hip/hip_runtime.h>
#include <hip/hip_bf16.h>
#include <cmath>

#define BB 16
#define TT 8192
#define MM (BB*TT)
#define FF 256
#define TBF 5.0f
#define PROJN 29

typedef __attribute__((ext_vector_type(8))) short short8;
typedef __attribute__((ext_vector_type(4))) float f32x4;

__device__ __forceinline__ float gelu_exact(float x){
    return 0.5f*x*(1.0f + erff(x*0.70710678118654752440f));
}
__device__ __forceinline__ float softplusf_(float v){
    return fmaxf(v,0.0f) + log1pf(expf(-fabsf(v)));
}
__device__ __forceinline__ float wred64(float v){
    #pragma unroll
    for(int o=32;o>0;o>>=1) v += __shfl_xor(v,o,64);
    return v;
}
__device__ __forceinline__ unsigned pack2bf(float a, float b){
    __hip_bfloat16 ha = __float2bfloat16(a);
    __hip_bfloat16 hb = __float2bfloat16(b);
    const unsigned ua = *reinterpret_cast<const unsigned short*>(&ha);
    const unsigned ub = *reinterpret_cast<const unsigned short*>(&hb);
    return ua | (ub<<16);
}

// h[m][f] = x0[m]*w_pre[f] + b_pre[f]
__global__ __launch_bounds__(256) void pre_kernel(
    const float* __restrict__ x, const float* __restrict__ w_pre,
    const float* __restrict__ b_pre, float* __restrict__ h)
{
    const int idx = blockIdx.x*256 + threadIdx.x;   // float4 index over M*64
    const int m = idx>>6, c = idx&63;
    const float x0 = x[(size_t)m*2];
    const float4 w  = ((const float4*)w_pre)[c];
    const float4 bb = ((const float4*)b_pre)[c];
    float4 o;
    o.x=fmaf(x0,w.x,bb.x); o.y=fmaf(x0,w.y,bb.y);
    o.z=fmaf(x0,w.z,bb.z); o.w=fmaf(x0,w.w,bb.w);
    ((float4*)h)[(size_t)idx] = o;
}

// Per layer: wimg[kc][n][40] bf16; [n][kp] = w11[kc*32+kp][n] (kp<32), pad kp 32..39 = 0.
// This is exactly the linear LDS image the layer kernel stages with global_load_lds.
__global__ __launch_bounds__(256) void wprep_kernel(
    const float* __restrict__ w11, __hip_bfloat16* __restrict__ wimg)
{
    const int layer = blockIdx.x>>3, kc = blockIdx.x&7;
    const float* __restrict__ w = w11 + (size_t)layer*FF*FF;
    __hip_bfloat16* __restrict__ o = wimg + (size_t)layer*81920 + kc*10240;
    for(int i=threadIdx.x; i<10240; i+=256){
        const int n = i/40, kp = i - n*40;
        const float v = (kp<32) ? w[(size_t)(kc*32+kp)*FF + n] : 0.0f;
        o[i] = __float2bfloat16(v);
    }
}

// One layer, 64 rows x 256 cols per block, 4 waves, bf16 MFMA 16x16x32.
__global__ __launch_bounds__(256,2) void layer_kernel(
    const float* __restrict__ hin, float* __restrict__ hout,
    const float* __restrict__ mask,
    const float* __restrict__ dwk, const float* __restrict__ dwb,
    const float* __restrict__ g1, const float* __restrict__ b1,
    const __hip_bfloat16* __restrict__ wimgL, const float* __restrict__ b11,
    const float* __restrict__ g2, const float* __restrict__ b2,
    const int dil)
{
    __shared__ __hip_bfloat16 ytile[64][264];     // +8 bf16 pad -> 2-way (free) conflicts
    __shared__ __hip_bfloat16 wbuf[2][256*40];    // double-buffered wT chunk images
    __shared__ float redS[64][4];
    __shared__ float redQ[64][4];
    __shared__ float stat[64][2];

    const int tid  = threadIdx.x;
    const int wave = tid>>6, lane = tid&63;
    const int l15  = lane&15, qq = lane>>4;

    int bid = blockIdx.x;                          // XCD-bijective swizzle (2048%8==0)
    bid = (bid&7)*((int)gridDim.x>>3) + (bid>>3);
    const int m0 = bid*64;
    const int b  = m0/TT;
    const int t0 = m0 - b*TT;
    const float* __restrict__ mrow = mask + (size_t)b*TT;

    // stage chunk kc into wbuf[bufp]: 20 KiB linear copy, 5 x 1KiB per wave
    #define STAGE(bufp, kc) do{ \
        const char* srcb = (const char*)wimgL + (size_t)(kc)*20480 + (wave*5)*1024 + lane*16; \
        char* dstb = (char*)&wbuf[(bufp)][0] + (wave*5)*1024; \
        _Pragma("unroll") \
        for(int q2=0;q2<5;++q2){ \
            __builtin_amdgcn_global_load_lds( \
                (const __attribute__((address_space(1))) void*)(srcb + q2*1024), \
                (__attribute__((address_space(3))) void*)(dstb + q2*1024), 16, 0, 0); \
        } }while(0)

    STAGE(0, 0);   // chunk-0 load hides under the conv phase

    // ---- Phase 1: conv + LN1 + gelu -> ytile (bf16). Wave handles rows wave*16..+15.
    const int f0 = lane*4;
    const float4 k0 = *(const float4*)&dwk[f0];
    const float4 k1 = *(const float4*)&dwk[FF+f0];
    const float4 k2 = *(const float4*)&dwk[2*FF+f0];
    const float4 cb = *(const float4*)&dwb[f0];
    const float4 g1v= *(const float4*)&g1[f0];
    const float4 b1v= *(const float4*)&b1[f0];

    for(int rr=0; rr<16; ++rr){
        const int r = wave*16+rr;
        const int m = m0+r, t = t0+r;
        const float4 hc = *(const float4*)&hin[(size_t)m*FF + f0];
        const float mkc = mrow[t];
        float4 a;
        a.x = fmaf(hc.x*mkc, k1.x, cb.x);
        a.y = fmaf(hc.y*mkc, k1.y, cb.y);
        a.z = fmaf(hc.z*mkc, k1.z, cb.z);
        a.w = fmaf(hc.w*mkc, k1.w, cb.w);
        if(t >= dil){
            const float4 hl = *(const float4*)&hin[(size_t)(m-dil)*FF + f0];
            const float mkl = mrow[t-dil];
            a.x = fmaf(hl.x*mkl, k0.x, a.x);
            a.y = fmaf(hl.y*mkl, k0.y, a.y);
            a.z = fmaf(hl.z*mkl, k0.z, a.z);
            a.w = fmaf(hl.w*mkl, k0.w, a.w);
        }
        if(t+dil < TT){
            const float4 hr = *(const float4*)&hin[(size_t)(m+dil)*FF + f0];
            const float mkr = mrow[t+dil];
            a.x = fmaf(hr.x*mkr, k2.x, a.x);
            a.y = fmaf(hr.y*mkr, k2.y, a.y);
            a.z = fmaf(hr.z*mkr, k2.z, a.z);
            a.w = fmaf(hr.w*mkr, k2.w, a.w);
        }
        const float mean = wred64(a.x+a.y+a.z+a.w)*(1.0f/FF);
        const float d0=a.x-mean, d1=a.y-mean, d2=a.z-mean, d3=a.w-mean;
        const float sq = wred64(d0*d0+d1*d1+d2*d2+d3*d3);
        const float rs = rsqrtf(sq*(1.0f/FF) + 1e-5f);
        const float y0 = gelu_exact(fmaf(d0*rs, g1v.x, b1v.x));
        const float y1 = gelu_exact(fmaf(d1*rs, g1v.y, b1v.y));
        const float y2 = gelu_exact(fmaf(d2*rs, g1v.z, b1v.z));
        const float y3 = gelu_exact(fmaf(d3*rs, g1v.w, b1v.w));
        *(uint2*)&ytile[r][f0] = make_uint2(pack2bf(y0,y1), pack2bf(y2,y3));
    }

    // ---- Phase 2: MFMA GEMM. Wave owns all 64 rows x cols [wave*64, wave*64+64).
    const int wc = wave*64;
    f32x4 acc[4][4];
    #pragma unroll
    for(int mf=0;mf<4;++mf)
        #pragma unroll
        for(int nf=0;nf<4;++nf)
            acc[mf][nf] = (f32x4){0.f,0.f,0.f,0.f};

    for(int kc=0;kc<8;++kc){
        const int cur = kc&1;
        if(kc<7){
            STAGE(cur^1, kc+1);
            asm volatile("s_waitcnt vmcnt(5) lgkmcnt(0)" ::: "memory");
        } else {
            asm volatile("s_waitcnt vmcnt(0) lgkmcnt(0)" ::: "memory");
        }
        __builtin_amdgcn_s_barrier();
        __builtin_amdgcn_sched_barrier(0);
        short8 af[4];
        #pragma unroll
        for(int mf=0;mf<4;++mf)
            af[mf] = *(const short8*)&ytile[mf*16+l15][kc*32 + qq*8];
        #pragma unroll
        for(int nf=0;nf<4;++nf){
            const short8 bfv = *(const short8*)&wbuf[cur][(wc+nf*16+l15)*40 + qq*8];
            #pragma unroll
            for(int mf=0;mf<4;++mf)
                acc[mf][nf] = __builtin_amdgcn_mfma_f32_16x16x32_bf16(af[mf], bfv, acc[mf][nf], 0,0,0);
        }
        __builtin_amdgcn_sched_barrier(0);
        __builtin_amdgcn_s_barrier();   // protect wbuf[cur] before next-iter STAGE overwrites
    }
    #undef STAGE

    // ---- Phase 3: +b11, LN2 (cross-wave), gelu, residual, store.
    float b11c[4], g2c[4], b2c[4];
    #pragma unroll
    for(int nf=0;nf<4;++nf){
        const int col = wc + nf*16 + l15;
        b11c[nf]=b11[col]; g2c[nf]=g2[col]; b2c[nf]=b2[col];
    }
    #pragma unroll
    for(int mf=0;mf<4;++mf){
        #pragma unroll
        for(int rg=0;rg<4;++rg){
            float s=0.f, sq=0.f;
            #pragma unroll
            for(int nf=0;nf<4;++nf){
                const float v = acc[mf][nf][rg] + b11c[nf];
                s += v; sq = fmaf(v,v,sq);
            }
            #pragma unroll
            for(int o=1;o<16;o<<=1){ s += __shfl_xor(s,o,64); sq += __shfl_xor(sq,o,64); }
            if(l15==0){
                const int row = mf*16 + qq*4 + rg;
                redS[row][wave]=s; redQ[row][wave]=sq;
            }
        }
    }
    __syncthreads();
    if(tid < 64){
        const float s  = redS[tid][0]+redS[tid][1]+redS[tid][2]+redS[tid][3];
        const float q2 = redQ[tid][0]+redQ[tid][1]+redQ[tid][2]+redQ[tid][3];
        const float mean = s*(1.0f/FF);
        const float var  = fmaf(-mean, mean, q2*(1.0f/FF));
        stat[tid][0]=mean; stat[tid][1]=rsqrtf(var+1e-5f);
    }
    __syncthreads();
    #pragma unroll
    for(int mf=0;mf<4;++mf){
        #pragma unroll
        for(int rg=0;rg<4;++rg){
            const int row = mf*16 + qq*4 + rg;
            const float mean = stat[row][0], rs = stat[row][1];
            const size_t gbase = (size_t)(m0+row)*FF;
            #pragma unroll
            for(int nf=0;nf<4;++nf){
                const int col = wc + nf*16 + l15;
                const float v  = acc[mf][nf][rg] + b11c[nf];
                const float yn = fmaf((v-mean)*rs, g2c[nf], b2c[nf]);
                hout[gbase+col] = hin[gbase+col] + gelu_exact(yn);
            }
        }
    }
}

// P[m][0..28] = ((h[m]*mask) @ w_proj + b_proj) * mask   (P padded to stride 32)
__global__ __launch_bounds__(256) void proj_kernel(
    const float* __restrict__ hin, const float* __restrict__ mask,
    const float* __restrict__ wproj, const float* __restrict__ bproj,
    float* __restrict__ P)
{
    __shared__ float htile[32][260];
    __shared__ float wp[256][32];
    const int tid = threadIdx.x;
    #pragma unroll
    for(int it=0; it<32; ++it){
        const int idx = it*256+tid;
        const int k = idx>>5, c = idx&31;
        wp[k][c] = (c<PROJN)? wproj[k*PROJN+c] : 0.0f;
    }
    const int m0 = blockIdx.x*32;
    #pragma unroll
    for(int it=0; it<8; ++it){
        const int idx = it*256+tid;
        const int r = idx>>6, c4 = idx&63;
        const float mk = mask[m0+r];
        float4 v = ((const float4*)hin)[(size_t)m0*64 + idx];
        v.x*=mk; v.y*=mk; v.z*=mk; v.w*=mk;
        ((float4*)&htile[r][0])[c4] = v;
    }
    __syncthreads();
    const int row = tid>>3, cg = tid&7, c0 = cg*4;
    float4 acc = make_float4(0.f,0.f,0.f,0.f);
    for(int k=0;k<256;++k){
        const float hb = htile[row][k];
        const float4 wv = ((const float4*)&wp[k][0])[cg];
        acc.x=fmaf(hb,wv.x,acc.x);
        acc.y=fmaf(hb,wv.y,acc.y);
        acc.z=fmaf(hb,wv.z,acc.z);
        acc.w=fmaf(hb,wv.w,acc.w);
    }
    const int m = m0+row;
    const float mk = mask[m];
    float4 bp;
    bp.x = bproj[c0];
    bp.y = (c0+1<PROJN)? bproj[c0+1]:0.0f;
    bp.z = (c0+2<PROJN)? bproj[c0+2]:0.0f;
    bp.w = (c0+3<PROJN)? bproj[c0+3]:0.0f;
    float4 o;
    o.x=(acc.x+bp.x)*mk; o.y=(acc.y+bp.y)*mk;
    o.z=(acc.z+bp.z)*mk; o.w=(acc.w+bp.w)*mk;
    ((float4*)P)[(size_t)m*8 + cg] = o;
}

// Rational-quadratic spline per (b,t); writes xo and block-reduced logdet
__global__ __launch_bounds__(256) void spline_kernel(
    const float* __restrict__ P, const float* __restrict__ x,
    const float* __restrict__ mask, float* __restrict__ out,
    float* __restrict__ logdet)
{
    const int tid = threadIdx.x;
    const int m = blockIdx.x*256 + tid;
    float p[32];
    #pragma unroll
    for(int j=0;j<8;++j) ((float4*)p)[j] = ((const float4*)P)[(size_t)m*8+j];
    const float x0 = x[(size_t)m*2];
    const float x1 = x[(size_t)m*2+1];
    const float mk = mask[m];
    const float sc = 0.0625f;

    float cw[11], ch[11], d[11];
    {
        float mx=-1e30f;
        #pragma unroll
        for(int j=0;j<10;++j) mx = fmaxf(mx, p[j]);
        float e[10]; float se=0.f;
        #pragma unroll
        for(int j=0;j<10;++j){ e[j]=expf((p[j]-mx)*sc); se+=e[j]; }
        const float inv = 1.0f/se;
        float cum=0.f;
        cw[0]=-TBF;
        #pragma unroll
        for(int j=0;j<10;++j){ cum += fmaf(0.99f, e[j]*inv, 0.001f); cw[j+1]=fmaf(2.0f*TBF,cum,-TBF); }
        cw[10]=TBF;
    }
    {
        float mx=-1e30f;
        #pragma unroll
        for(int j=0;j<10;++j) mx = fmaxf(mx, p[10+j]);
        float e[10]; float se=0.f;
        #pragma unroll
        for(int j=0;j<10;++j){ e[j]=expf((p[10+j]-mx)*sc); se+=e[j]; }
        const float inv = 1.0f/se;
        float cum=0.f;
        ch[0]=-TBF;
        #pragma unroll
        for(int j=0;j<10;++j){ cum += fmaf(0.99f, e[j]*inv, 0.001f); ch[j+1]=fmaf(2.0f*TBF,cum,-TBF); }
        ch[10]=TBF;
    }
    d[0]=1.0f; d[10]=1.0f;
    #pragma unroll
    for(int k=1;k<10;++k) d[k] = 0.001f + softplusf_(p[19+k]);

    const bool inside = (x1>=-TBF)&&(x1<=TBF);
    const float xc = fminf(fmaxf(x1,-TBF),TBF);

    float icw=cw[0], ibw=cw[1]-cw[0], ich=ch[0], ibh=ch[1]-ch[0], dk=d[0], dk1=d[1];
    #pragma unroll
    for(int j=1;j<10;++j){
        const bool sel = (xc>=cw[j]);
        icw = sel? cw[j]      : icw;
        ibw = sel? cw[j+1]-cw[j] : ibw;
        ich = sel? ch[j]      : ich;
        ibh = sel? ch[j+1]-ch[j] : ibh;
        dk  = sel? d[j]       : dk;
        dk1 = sel? d[j+1]     : dk1;
    }

    const float delta = ibh/ibw;
    const float th = (xc-icw)/ibw;
    const float th1m = th*(1.0f-th);
    const float denom = fmaf(fmaf(-2.0f,delta,dk+dk1), th1m, delta);
    const float num = ibh*fmaf(delta*th, th, dk*th1m);
    const float yv = ich + num/denom;
    const float omt = 1.0f-th;
    const float dnum = delta*delta*(dk1*th*th + 2.0f*delta*th1m + dk*omt*omt);
    const float lad = logf(dnum) - 2.0f*logf(denom);
    const float y1 = inside? yv : x1;
    const float lv = inside? lad : 0.0f;

    out[(size_t)m*2]   = x0*mk;
    out[(size_t)m*2+1] = y1*mk;

    __shared__ float red[256];
    red[tid]=lv*mk;
    __syncthreads();
    #pragma unroll
    for(int s=128;s>0;s>>=1){ if(tid<s) red[tid]+=red[tid+s]; __syncthreads(); }
    if(tid==0) atomicAdd(&logdet[blockIdx.x>>5], red[0]);
}

extern "C" void kernel_launch(void* const* d_in, const int* in_sizes, int n_in,
                              void* d_out, int out_size, void* d_ws, size_t ws_size,
                              hipStream_t stream)
{
    const float* x      = (const float*)d_in[0];
    const float* mask   = (const float*)d_in[1];
    const float* w_pre  = (const float*)d_in[2];
    const float* b_pre  = (const float*)d_in[3];
    const float* dw_k   = (const float*)d_in[4];
    const float* dw_b   = (const float*)d_in[5];
    const float* w11    = (const float*)d_in[6];
    const float* b11    = (const float*)d_in[7];
    const float* ln1g   = (const float*)d_in[8];
    const float* ln1b   = (const float*)d_in[9];
    const float* ln2g   = (const float*)d_in[10];
    const float* ln2b   = (const float*)d_in[11];
    const float* w_proj = (const float*)d_in[12];
    const float* b_proj = (const float*)d_in[13];

    const size_t hbytes = (size_t)MM*FF*4;          // 128 MiB
    float* h0 = (float*)d_ws;
    float* h1 = h0 + (size_t)MM*FF;
    float* P  = h0;                                  // overlay after layers are done
    float* outp   = (float*)d_out;
    float* logdet = outp + (size_t)MM*2;

    // bf16 transposed+padded weight images: 3 x 160 KiB. Prefer ws tail; else
    // use d_out as pre-spline scratch (spline fully rewrites d_out afterwards).
    __hip_bfloat16* wimg;
    if(ws_size >= 2*hbytes + 3*163840)
        wimg = (__hip_bfloat16*)((char*)d_ws + 2*hbytes);
    else
        wimg = (__hip_bfloat16*)d_out;

    wprep_kernel<<<24, 256, 0, stream>>>(w11, wimg);
    pre_kernel<<<MM*64/256, 256, 0, stream>>>(x, w_pre, b_pre, h0);

    const int dils[3] = {1,3,9};
    const float* hi[3] = {h0, h1, h0};
    float*       ho[3] = {h1, h0, h1};
    for(int i=0;i<3;++i){
        layer_kernel<<<MM/64, 256, 0, stream>>>(
            hi[i], ho[i], mask,
            dw_k + (size_t)i*3*FF, dw_b + (size_t)i*FF,
            ln1g + (size_t)i*FF,  ln1b + (size_t)i*FF,
            wimg + (size_t)i*81920, b11 + (size_t)i*FF,
            ln2g + (size_t)i*FF,  ln2b + (size_t)i*FF,
            dils[i]);
    }

    proj_kernel<<<MM/32, 256, 0, stream>>>(h1, mask, w_proj, b_proj, P);

    hipMemsetAsync(logdet, 0, BB*sizeof(float), stream);
    spline_kernel<<<MM/256, 256, 0, stream>>>(P, x, mask, outp, logdet);
}

// Round 5
// 558.973 us; speedup vs baseline: 5.4276x; 1.4158x over previous
//
#include <hip/hip_runtime.h>
#include <hip/hip_bf16.h>
#include <cmath>

#define BB 16
#define TT 8192
#define MM (BB*TT)
#define FF 256
#define TBF 5.0f
#define PROJN 29

typedef __attribute__((ext_vector_type(8))) short short8;
typedef __attribute__((ext_vector_type(4))) float f32x4;

__device__ __forceinline__ float gelu_exact(float x){
    return 0.5f*x*(1.0f + erff(x*0.70710678118654752440f));
}
__device__ __forceinline__ float softplusf_(float v){
    return fmaxf(v,0.0f) + log1pf(expf(-fabsf(v)));
}
__device__ __forceinline__ unsigned pack2bf(float a, float b){
    __hip_bfloat16 ha = __float2bfloat16(a);
    __hip_bfloat16 hb = __float2bfloat16(b);
    const unsigned ua = *reinterpret_cast<const unsigned short*>(&ha);
    const unsigned ub = *reinterpret_cast<const unsigned short*>(&hb);
    return ua | (ub<<16);
}

// Per layer: wimg[kc][n][40] bf16; [n][kp] = w11[kc*32+kp][n] (kp<32), pad kp 32..39 = 0.
__global__ __launch_bounds__(256) void wprep_kernel(
    const float* __restrict__ w11, __hip_bfloat16* __restrict__ wimg)
{
    const int layer = blockIdx.x>>3, kc = blockIdx.x&7;
    const float* __restrict__ w = w11 + (size_t)layer*FF*FF;
    __hip_bfloat16* __restrict__ o = wimg + (size_t)layer*81920 + kc*10240;
    for(int i=threadIdx.x; i<10240; i+=256){
        const int n = i/40, kp = i - n*40;
        const float v = (kp<32) ? w[(size_t)(kc*32+kp)*FF + n] : 0.0f;
        o[i] = __float2bfloat16(v);
    }
}

// One layer, 64 rows x 256 cols per block, 4 waves, bf16 MFMA 16x16x32.
// B-fragments read straight from L2-resident wimg (no LDS staging, 3 barriers total).
// pre_mode: layer-0 input h = x0*w_pre + b_pre computed on the fly (rank-1).
__global__ __launch_bounds__(256,4) void layer_kernel(
    const float* __restrict__ hin, float* __restrict__ hout,
    const float* __restrict__ xsrc,
    const float* __restrict__ w_pre, const float* __restrict__ b_pre,
    const float* __restrict__ mask,
    const float* __restrict__ dwk, const float* __restrict__ dwb,
    const float* __restrict__ g1, const float* __restrict__ b1,
    const __hip_bfloat16* __restrict__ wimgL, const float* __restrict__ b11,
    const float* __restrict__ g2, const float* __restrict__ b2,
    const int dil, const int pre_mode)
{
    __shared__ __hip_bfloat16 ytile[64][264];     // +8 bf16 pad
    __shared__ float redS[64][4];
    __shared__ float redQ[64][4];
    __shared__ float stat[64][2];

    const int tid  = threadIdx.x;
    const int wave = tid>>6, lane = tid&63;
    const int l15  = lane&15, qq = lane>>4;

    int bid = blockIdx.x;                          // XCD-bijective swizzle (2048%8==0)
    bid = (bid&7)*((int)gridDim.x>>3) + (bid>>3);
    const int m0 = bid*64;
    const int b  = m0/TT;
    const int t0 = m0 - b*TT;
    const float* __restrict__ mrow = mask + (size_t)b*TT;

    // ---- Phase 1: conv + LN1 + gelu -> ytile (bf16). Wave handles rows wave*16..+15.
    const int f0 = lane*4;
    const float4 k0 = *(const float4*)&dwk[f0];
    const float4 k1 = *(const float4*)&dwk[FF+f0];
    const float4 k2 = *(const float4*)&dwk[2*FF+f0];
    const float4 cb = *(const float4*)&dwb[f0];
    const float4 g1v= *(const float4*)&g1[f0];
    const float4 b1v= *(const float4*)&b1[f0];
    float4 wp4, bp4;
    if(pre_mode){ wp4 = *(const float4*)&w_pre[f0]; bp4 = *(const float4*)&b_pre[f0]; }

    for(int rr=0; rr<16; ++rr){
        const int r = wave*16+rr;
        const int m = m0+r, t = t0+r;
        float4 hc;
        if(pre_mode){
            const float xv = xsrc[(size_t)m*2];
            hc.x=fmaf(xv,wp4.x,bp4.x); hc.y=fmaf(xv,wp4.y,bp4.y);
            hc.z=fmaf(xv,wp4.z,bp4.z); hc.w=fmaf(xv,wp4.w,bp4.w);
        } else {
            hc = *(const float4*)&hin[(size_t)m*FF + f0];
        }
        const float mkc = mrow[t];
        float4 a;
        a.x = fmaf(hc.x*mkc, k1.x, cb.x);
        a.y = fmaf(hc.y*mkc, k1.y, cb.y);
        a.z = fmaf(hc.z*mkc, k1.z, cb.z);
        a.w = fmaf(hc.w*mkc, k1.w, cb.w);
        if(t >= dil){
            float4 hl;
            if(pre_mode){
                const float xv = xsrc[(size_t)(m-dil)*2];
                hl.x=fmaf(xv,wp4.x,bp4.x); hl.y=fmaf(xv,wp4.y,bp4.y);
                hl.z=fmaf(xv,wp4.z,bp4.z); hl.w=fmaf(xv,wp4.w,bp4.w);
            } else {
                hl = *(const float4*)&hin[(size_t)(m-dil)*FF + f0];
            }
            const float mkl = mrow[t-dil];
            a.x = fmaf(hl.x*mkl, k0.x, a.x);
            a.y = fmaf(hl.y*mkl, k0.y, a.y);
            a.z = fmaf(hl.z*mkl, k0.z, a.z);
            a.w = fmaf(hl.w*mkl, k0.w, a.w);
        }
        if(t+dil < TT){
            float4 hr;
            if(pre_mode){
                const float xv = xsrc[(size_t)(m+dil)*2];
                hr.x=fmaf(xv,wp4.x,bp4.x); hr.y=fmaf(xv,wp4.y,bp4.y);
                hr.z=fmaf(xv,wp4.z,bp4.z); hr.w=fmaf(xv,wp4.w,bp4.w);
            } else {
                hr = *(const float4*)&hin[(size_t)(m+dil)*FF + f0];
            }
            const float mkr = mrow[t+dil];
            a.x = fmaf(hr.x*mkr, k2.x, a.x);
            a.y = fmaf(hr.y*mkr, k2.y, a.y);
            a.z = fmaf(hr.z*mkr, k2.z, a.z);
            a.w = fmaf(hr.w*mkr, k2.w, a.w);
        }
        // single-pass LN1: sum and sum-of-squares reduced together (ILP)
        float s  = a.x+a.y+a.z+a.w;
        float sq = fmaf(a.x,a.x, fmaf(a.y,a.y, fmaf(a.z,a.z, a.w*a.w)));
        #pragma unroll
        for(int o=32;o>0;o>>=1){
            s  += __shfl_xor(s,o,64);
            sq += __shfl_xor(sq,o,64);
        }
        const float mean = s*(1.0f/FF);
        const float var  = fmaf(-mean, mean, sq*(1.0f/FF));
        const float rs = rsqrtf(var + 1e-5f);
        const float y0 = gelu_exact(fmaf((a.x-mean)*rs, g1v.x, b1v.x));
        const float y1 = gelu_exact(fmaf((a.y-mean)*rs, g1v.y, b1v.y));
        const float y2 = gelu_exact(fmaf((a.z-mean)*rs, g1v.z, b1v.z));
        const float y3 = gelu_exact(fmaf((a.w-mean)*rs, g1v.w, b1v.w));
        *(uint2*)&ytile[r][f0] = make_uint2(pack2bf(y0,y1), pack2bf(y2,y3));
    }

    __syncthreads();   // ytile complete (cross-wave A reads follow)

    // ---- Phase 2: MFMA GEMM. Wave owns all 64 rows x cols [wave*64, wave*64+64).
    // B-fragments from global wimg (L2-resident, identical across blocks).
    const int wc = wave*64;
    f32x4 acc[4][4];
    #pragma unroll
    for(int mf=0;mf<4;++mf)
        #pragma unroll
        for(int nf=0;nf<4;++nf)
            acc[mf][nf] = (f32x4){0.f,0.f,0.f,0.f};

    #pragma unroll
    for(int kc=0;kc<8;++kc){
        short8 bfv[4];
        #pragma unroll
        for(int nf=0;nf<4;++nf)
            bfv[nf] = *(const short8*)&wimgL[(size_t)kc*10240 + (wc+nf*16+l15)*40 + qq*8];
        short8 af[4];
        #pragma unroll
        for(int mf=0;mf<4;++mf)
            af[mf] = *(const short8*)&ytile[mf*16+l15][kc*32 + qq*8];
        #pragma unroll
        for(int nf=0;nf<4;++nf)
            #pragma unroll
            for(int mf=0;mf<4;++mf)
                acc[mf][nf] = __builtin_amdgcn_mfma_f32_16x16x32_bf16(af[mf], bfv[nf], acc[mf][nf], 0,0,0);
    }

    // ---- Phase 3: +b11, LN2 (cross-wave), gelu, residual, store.
    float b11c[4], g2c[4], b2c[4], wpc[4], bpc[4];
    #pragma unroll
    for(int nf=0;nf<4;++nf){
        const int col = wc + nf*16 + l15;
        b11c[nf]=b11[col]; g2c[nf]=g2[col]; b2c[nf]=b2[col];
        if(pre_mode){ wpc[nf]=w_pre[col]; bpc[nf]=b_pre[col]; }
    }
    #pragma unroll
    for(int mf=0;mf<4;++mf){
        #pragma unroll
        for(int rg=0;rg<4;++rg){
            float s=0.f, sq=0.f;
            #pragma unroll
            for(int nf=0;nf<4;++nf){
                const float v = acc[mf][nf][rg] + b11c[nf];
                s += v; sq = fmaf(v,v,sq);
            }
            #pragma unroll
            for(int o=1;o<16;o<<=1){ s += __shfl_xor(s,o,64); sq += __shfl_xor(sq,o,64); }
            if(l15==0){
                const int row = mf*16 + qq*4 + rg;
                redS[row][wave]=s; redQ[row][wave]=sq;
            }
        }
    }
    __syncthreads();
    if(tid < 64){
        const float s  = redS[tid][0]+redS[tid][1]+redS[tid][2]+redS[tid][3];
        const float q2 = redQ[tid][0]+redQ[tid][1]+redQ[tid][2]+redQ[tid][3];
        const float mean = s*(1.0f/FF);
        const float var  = fmaf(-mean, mean, q2*(1.0f/FF));
        stat[tid][0]=mean; stat[tid][1]=rsqrtf(var+1e-5f);
    }
    __syncthreads();
    #pragma unroll
    for(int mf=0;mf<4;++mf){
        #pragma unroll
        for(int rg=0;rg<4;++rg){
            const int row = mf*16 + qq*4 + rg;
            const float mean = stat[row][0], rs = stat[row][1];
            const size_t gbase = (size_t)(m0+row)*FF;
            float x0r = 0.0f;
            if(pre_mode) x0r = xsrc[(size_t)(m0+row)*2];
            #pragma unroll
            for(int nf=0;nf<4;++nf){
                const int col = wc + nf*16 + l15;
                const float v  = acc[mf][nf][rg] + b11c[nf];
                const float yn = fmaf((v-mean)*rs, g2c[nf], b2c[nf]);
                const float hres = pre_mode ? fmaf(x0r, wpc[nf], bpc[nf]) : hin[gbase+col];
                hout[gbase+col] = hres + gelu_exact(yn);
            }
        }
    }
}

// P[m][0..28] = ((h[m]*mask) @ w_proj + b_proj) * mask   (P padded to stride 32)
__global__ __launch_bounds__(256) void proj_kernel(
    const float* __restrict__ hin, const float* __restrict__ mask,
    const float* __restrict__ wproj, const float* __restrict__ bproj,
    float* __restrict__ P)
{
    __shared__ float htile[32][260];
    __shared__ float wp[256][32];
    const int tid = threadIdx.x;
    #pragma unroll
    for(int it=0; it<32; ++it){
        const int idx = it*256+tid;
        const int k = idx>>5, c = idx&31;
        wp[k][c] = (c<PROJN)? wproj[k*PROJN+c] : 0.0f;
    }
    const int m0 = blockIdx.x*32;
    #pragma unroll
    for(int it=0; it<8; ++it){
        const int idx = it*256+tid;
        const int r = idx>>6, c4 = idx&63;
        const float mk = mask[m0+r];
        float4 v = ((const float4*)hin)[(size_t)m0*64 + idx];
        v.x*=mk; v.y*=mk; v.z*=mk; v.w*=mk;
        ((float4*)&htile[r][0])[c4] = v;
    }
    __syncthreads();
    const int row = tid>>3, cg = tid&7, c0 = cg*4;
    float4 acc = make_float4(0.f,0.f,0.f,0.f);
    for(int k=0;k<256;++k){
        const float hb = htile[row][k];
        const float4 wv = ((const float4*)&wp[k][0])[cg];
        acc.x=fmaf(hb,wv.x,acc.x);
        acc.y=fmaf(hb,wv.y,acc.y);
        acc.z=fmaf(hb,wv.z,acc.z);
        acc.w=fmaf(hb,wv.w,acc.w);
    }
    const int m = m0+row;
    const float mk = mask[m];
    float4 bp;
    bp.x = bproj[c0];
    bp.y = (c0+1<PROJN)? bproj[c0+1]:0.0f;
    bp.z = (c0+2<PROJN)? bproj[c0+2]:0.0f;
    bp.w = (c0+3<PROJN)? bproj[c0+3]:0.0f;
    float4 o;
    o.x=(acc.x+bp.x)*mk; o.y=(acc.y+bp.y)*mk;
    o.z=(acc.z+bp.z)*mk; o.w=(acc.w+bp.w)*mk;
    ((float4*)P)[(size_t)m*8 + cg] = o;
}

// Rational-quadratic spline per (b,t); writes xo and block-reduced logdet
__global__ __launch_bounds__(256) void spline_kernel(
    const float* __restrict__ P, const float* __restrict__ x,
    const float* __restrict__ mask, float* __restrict__ out,
    float* __restrict__ logdet)
{
    const int tid = threadIdx.x;
    const int m = blockIdx.x*256 + tid;
    float p[32];
    #pragma unroll
    for(int j=0;j<8;++j) ((float4*)p)[j] = ((const float4*)P)[(size_t)m*8+j];
    const float x0 = x[(size_t)m*2];
    const float x1 = x[(size_t)m*2+1];
    const float mk = mask[m];
    const float sc = 0.0625f;

    float cw[11], ch[11], d[11];
    {
        float mx=-1e30f;
        #pragma unroll
        for(int j=0;j<10;++j) mx = fmaxf(mx, p[j]);
        float e[10]; float se=0.f;
        #pragma unroll
        for(int j=0;j<10;++j){ e[j]=expf((p[j]-mx)*sc); se+=e[j]; }
        const float inv = 1.0f/se;
        float cum=0.f;
        cw[0]=-TBF;
        #pragma unroll
        for(int j=0;j<10;++j){ cum += fmaf(0.99f, e[j]*inv, 0.001f); cw[j+1]=fmaf(2.0f*TBF,cum,-TBF); }
        cw[10]=TBF;
    }
    {
        float mx=-1e30f;
        #pragma unroll
        for(int j=0;j<10;++j) mx = fmaxf(mx, p[10+j]);
        float e[10]; float se=0.f;
        #pragma unroll
        for(int j=0;j<10;++j){ e[j]=expf((p[10+j]-mx)*sc); se+=e[j]; }
        const float inv = 1.0f/se;
        float cum=0.f;
        ch[0]=-TBF;
        #pragma unroll
        for(int j=0;j<10;++j){ cum += fmaf(0.99f, e[j]*inv, 0.001f); ch[j+1]=fmaf(2.0f*TBF,cum,-TBF); }
        ch[10]=TBF;
    }
    d[0]=1.0f; d[10]=1.0f;
    #pragma unroll
    for(int k=1;k<10;++k) d[k] = 0.001f + softplusf_(p[19+k]);

    const bool inside = (x1>=-TBF)&&(x1<=TBF);
    const float xc = fminf(fmaxf(x1,-TBF),TBF);

    float icw=cw[0], ibw=cw[1]-cw[0], ich=ch[0], ibh=ch[1]-ch[0], dk=d[0], dk1=d[1];
    #pragma unroll
    for(int j=1;j<10;++j){
        const bool sel = (xc>=cw[j]);
        icw = sel? cw[j]      : icw;
        ibw = sel? cw[j+1]-cw[j] : ibw;
        ich = sel? ch[j]      : ich;
        ibh = sel? ch[j+1]-ch[j] : ibh;
        dk  = sel? d[j]       : dk;
        dk1 = sel? d[j+1]     : dk1;
    }

    const float delta = ibh/ibw;
    const float th = (xc-icw)/ibw;
    const float th1m = th*(1.0f-th);
    const float denom = fmaf(fmaf(-2.0f,delta,dk+dk1), th1m, delta);
    const float num = ibh*fmaf(delta*th, th, dk*th1m);
    const float yv = ich + num/denom;
    const float omt = 1.0f-th;
    const float dnum = delta*delta*(dk1*th*th + 2.0f*delta*th1m + dk*omt*omt);
    const float lad = logf(dnum) - 2.0f*logf(denom);
    const float y1 = inside? yv : x1;
    const float lv = inside? lad : 0.0f;

    out[(size_t)m*2]   = x0*mk;
    out[(size_t)m*2+1] = y1*mk;

    __shared__ float red[256];
    red[tid]=lv*mk;
    __syncthreads();
    #pragma unroll
    for(int s=128;s>0;s>>=1){ if(tid<s) red[tid]+=red[tid+s]; __syncthreads(); }
    if(tid==0) atomicAdd(&logdet[blockIdx.x>>5], red[0]);
}

extern "C" void kernel_launch(void* const* d_in, const int* in_sizes, int n_in,
                              void* d_out, int out_size, void* d_ws, size_t ws_size,
                              hipStream_t stream)
{
    const float* x      = (const float*)d_in[0];
    const float* mask   = (const float*)d_in[1];
    const float* w_pre  = (const float*)d_in[2];
    const float* b_pre  = (const float*)d_in[3];
    const float* dw_k   = (const float*)d_in[4];
    const float* dw_b   = (const float*)d_in[5];
    const float* w11    = (const float*)d_in[6];
    const float* b11    = (const float*)d_in[7];
    const float* ln1g   = (const float*)d_in[8];
    const float* ln1b   = (const float*)d_in[9];
    const float* ln2g   = (const float*)d_in[10];
    const float* ln2b   = (const float*)d_in[11];
    const float* w_proj = (const float*)d_in[12];
    const float* b_proj = (const float*)d_in[13];

    const size_t hbytes = (size_t)MM*FF*4;          // 128 MiB
    float* h0 = (float*)d_ws;
    float* h1 = h0 + (size_t)MM*FF;
    float* P  = h0;                                  // overlay after layers are done
    float* outp   = (float*)d_out;
    float* logdet = outp + (size_t)MM*2;

    // bf16 transposed+padded weight images: 3 x 160 KiB. Prefer ws tail; else
    // use d_out as pre-spline scratch (spline fully rewrites d_out afterwards).
    __hip_bfloat16* wimg;
    if(ws_size >= 2*hbytes + 3*163840)
        wimg = (__hip_bfloat16*)((char*)d_ws + 2*hbytes);
    else
        wimg = (__hip_bfloat16*)d_out;

    wprep_kernel<<<24, 256, 0, stream>>>(w11, wimg);

    // layer 0 fuses the rank-1 pre-expansion (reads x directly); ping-pong after.
    // dil = 1, 3, 9
    layer_kernel<<<MM/64, 256, 0, stream>>>(
        (const float*)nullptr, h1, x, w_pre, b_pre, mask,
        dw_k, dw_b, ln1g, ln1b, wimg, b11, ln2g, ln2b, 1, 1);
    layer_kernel<<<MM/64, 256, 0, stream>>>(
        h1, h0, x, w_pre, b_pre, mask,
        dw_k + (size_t)3*FF, dw_b + (size_t)FF,
        ln1g + (size_t)FF, ln1b + (size_t)FF,
        wimg + (size_t)81920, b11 + (size_t)FF,
        ln2g + (size_t)FF, ln2b + (size_t)FF, 3, 0);
    layer_kernel<<<MM/64, 256, 0, stream>>>(
        h0, h1, x, w_pre, b_pre, mask,
        dw_k + (size_t)6*FF, dw_b + (size_t)2*FF,
        ln1g + (size_t)2*FF, ln1b + (size_t)2*FF,
        wimg + (size_t)2*81920, b11 + (size_t)2*FF,
        ln2g + (size_t)2*FF, ln2b + (size_t)2*FF, 9, 0);

    proj_kernel<<<MM/32, 256, 0, stream>>>(h1, mask, w_proj, b_proj, P);

    hipMemsetAsync(logdet, 0, BB*sizeof(float), stream);
    spline_kernel<<<MM/256, 256, 0, stream>>>(P, x, mask, outp, logdet);
}

// Round 6
// 484.341 us; speedup vs baseline: 6.2640x; 1.1541x over previous
//
#include <hip/hip_runtime.h>
#include <hip/hip_bf16.h>
#include <cmath>

#define BB 16
#define TT 8192
#define MM (BB*TT)
#define FF 256
#define TBF 5.0f
#define PROJN 29

typedef __attribute__((ext_vector_type(8))) short short8;
typedef __attribute__((ext_vector_type(4))) float f32x4;

// Branch-free erf (Abramowitz-Stegun 7.1.26, max abs err 1.5e-7).
__device__ __forceinline__ float gelu_exact(float x){
    const float z  = x*0.70710678118654752440f;
    const float az = fabsf(z);
    const float t  = __builtin_amdgcn_rcpf(fmaf(0.3275911f, az, 1.0f));
    float p = fmaf(1.061405429f, t, -1.453152027f);
    p = fmaf(p, t, 1.421413741f);
    p = fmaf(p, t, -0.284496736f);
    p = fmaf(p, t, 0.254829592f);
    p = p*t;
    const float e  = __expf(-az*az);
    const float r  = fmaf(-p, e, 1.0f);          // erf(|z|)
    const float er = copysignf(r, z);            // erf(z)
    return 0.5f*x*(1.0f + er);
}
__device__ __forceinline__ float softplusf_(float v){
    return fmaxf(v,0.0f) + log1pf(__expf(-fabsf(v)));
}
__device__ __forceinline__ unsigned pack2bf(float a, float b){
    __hip_bfloat16 ha = __float2bfloat16(a);
    __hip_bfloat16 hb = __float2bfloat16(b);
    const unsigned ua = *reinterpret_cast<const unsigned short*>(&ha);
    const unsigned ub = *reinterpret_cast<const unsigned short*>(&hb);
    return ua | (ub<<16);
}

// Layer images: wimg[layer][kc][n][40] bf16, [n][kp] = w11[kc*32+kp][n] (kp<32; pad 0).
// Proj image (blocks 24..31): wpimg[kc][n 0..31][40], [n][kp] = wproj[kc*32+kp][n] (n<29; pad 0).
__global__ __launch_bounds__(256) void wprep_kernel(
    const float* __restrict__ w11, const float* __restrict__ wproj,
    __hip_bfloat16* __restrict__ wimg, __hip_bfloat16* __restrict__ wpimg)
{
    if(blockIdx.x < 24){
        const int layer = blockIdx.x>>3, kc = blockIdx.x&7;
        const float* __restrict__ w = w11 + (size_t)layer*FF*FF;
        __hip_bfloat16* __restrict__ o = wimg + (size_t)layer*81920 + kc*10240;
        for(int i=threadIdx.x; i<10240; i+=256){
            const int n = i/40, kp = i - n*40;
            const float v = (kp<32) ? w[(size_t)(kc*32+kp)*FF + n] : 0.0f;
            o[i] = __float2bfloat16(v);
        }
    } else {
        const int kc = blockIdx.x - 24;
        __hip_bfloat16* __restrict__ o = wpimg + (size_t)kc*1280;
        for(int i=threadIdx.x; i<1280; i+=256){
            const int n = i/40, kp = i - n*40;
            const float v = (kp<32 && n<PROJN) ? wproj[(size_t)(kc*32+kp)*PROJN + n] : 0.0f;
            o[i] = __float2bfloat16(v);
        }
    }
}

// One layer, 64 rows x 256 cols per block, 4 waves, bf16 MFMA 16x16x32.
// B-fragments read straight from L2-resident wimg (no LDS staging).
// pre_mode: layer-0 input h = x0*w_pre + b_pre computed on the fly (rank-1).
__global__ __launch_bounds__(256,4) void layer_kernel(
    const float* __restrict__ hin, float* __restrict__ hout,
    const float* __restrict__ xsrc,
    const float* __restrict__ w_pre, const float* __restrict__ b_pre,
    const float* __restrict__ mask,
    const float* __restrict__ dwk, const float* __restrict__ dwb,
    const float* __restrict__ g1, const float* __restrict__ b1,
    const __hip_bfloat16* __restrict__ wimgL, const float* __restrict__ b11,
    const float* __restrict__ g2, const float* __restrict__ b2,
    const int dil, const int pre_mode)
{
    __shared__ __hip_bfloat16 ytile[64][264];     // +8 bf16 pad
    __shared__ float redS[64][4];
    __shared__ float redQ[64][4];
    __shared__ float stat[64][2];

    const int tid  = threadIdx.x;
    const int wave = tid>>6, lane = tid&63;
    const int l15  = lane&15, qq = lane>>4;

    int bid = blockIdx.x;                          // XCD-bijective swizzle (2048%8==0)
    bid = (bid&7)*((int)gridDim.x>>3) + (bid>>3);
    const int m0 = bid*64;
    const int b  = m0/TT;
    const int t0 = m0 - b*TT;
    const float* __restrict__ mrow = mask + (size_t)b*TT;

    // ---- Phase 1: conv + LN1 + gelu -> ytile (bf16). Wave handles rows wave*16..+15.
    const int f0 = lane*4;
    const float4 k0 = *(const float4*)&dwk[f0];
    const float4 k1 = *(const float4*)&dwk[FF+f0];
    const float4 k2 = *(const float4*)&dwk[2*FF+f0];
    const float4 cb = *(const float4*)&dwb[f0];
    const float4 g1v= *(const float4*)&g1[f0];
    const float4 b1v= *(const float4*)&b1[f0];
    float4 wp4, bp4;
    if(pre_mode){ wp4 = *(const float4*)&w_pre[f0]; bp4 = *(const float4*)&b_pre[f0]; }

    for(int rr=0; rr<16; ++rr){
        const int r = wave*16+rr;
        const int m = m0+r, t = t0+r;
        float4 hc;
        if(pre_mode){
            const float xv = xsrc[(size_t)m*2];
            hc.x=fmaf(xv,wp4.x,bp4.x); hc.y=fmaf(xv,wp4.y,bp4.y);
            hc.z=fmaf(xv,wp4.z,bp4.z); hc.w=fmaf(xv,wp4.w,bp4.w);
        } else {
            hc = *(const float4*)&hin[(size_t)m*FF + f0];
        }
        const float mkc = mrow[t];
        float4 a;
        a.x = fmaf(hc.x*mkc, k1.x, cb.x);
        a.y = fmaf(hc.y*mkc, k1.y, cb.y);
        a.z = fmaf(hc.z*mkc, k1.z, cb.z);
        a.w = fmaf(hc.w*mkc, k1.w, cb.w);
        if(t >= dil){
            float4 hl;
            if(pre_mode){
                const float xv = xsrc[(size_t)(m-dil)*2];
                hl.x=fmaf(xv,wp4.x,bp4.x); hl.y=fmaf(xv,wp4.y,bp4.y);
                hl.z=fmaf(xv,wp4.z,bp4.z); hl.w=fmaf(xv,wp4.w,bp4.w);
            } else {
                hl = *(const float4*)&hin[(size_t)(m-dil)*FF + f0];
            }
            const float mkl = mrow[t-dil];
            a.x = fmaf(hl.x*mkl, k0.x, a.x);
            a.y = fmaf(hl.y*mkl, k0.y, a.y);
            a.z = fmaf(hl.z*mkl, k0.z, a.z);
            a.w = fmaf(hl.w*mkl, k0.w, a.w);
        }
        if(t+dil < TT){
            float4 hr;
            if(pre_mode){
                const float xv = xsrc[(size_t)(m+dil)*2];
                hr.x=fmaf(xv,wp4.x,bp4.x); hr.y=fmaf(xv,wp4.y,bp4.y);
                hr.z=fmaf(xv,wp4.z,bp4.z); hr.w=fmaf(xv,wp4.w,bp4.w);
            } else {
                hr = *(const float4*)&hin[(size_t)(m+dil)*FF + f0];
            }
            const float mkr = mrow[t+dil];
            a.x = fmaf(hr.x*mkr, k2.x, a.x);
            a.y = fmaf(hr.y*mkr, k2.y, a.y);
            a.z = fmaf(hr.z*mkr, k2.z, a.z);
            a.w = fmaf(hr.w*mkr, k2.w, a.w);
        }
        // single-pass LN1: sum and sum-of-squares reduced together (ILP)
        float s  = a.x+a.y+a.z+a.w;
        float sq = fmaf(a.x,a.x, fmaf(a.y,a.y, fmaf(a.z,a.z, a.w*a.w)));
        #pragma unroll
        for(int o=32;o>0;o>>=1){
            s  += __shfl_xor(s,o,64);
            sq += __shfl_xor(sq,o,64);
        }
        const float mean = s*(1.0f/FF);
        const float var  = fmaf(-mean, mean, sq*(1.0f/FF));
        const float rs = rsqrtf(var + 1e-5f);
        const float y0 = gelu_exact(fmaf((a.x-mean)*rs, g1v.x, b1v.x));
        const float y1 = gelu_exact(fmaf((a.y-mean)*rs, g1v.y, b1v.y));
        const float y2 = gelu_exact(fmaf((a.z-mean)*rs, g1v.z, b1v.z));
        const float y3 = gelu_exact(fmaf((a.w-mean)*rs, g1v.w, b1v.w));
        *(uint2*)&ytile[r][f0] = make_uint2(pack2bf(y0,y1), pack2bf(y2,y3));
    }

    __syncthreads();   // ytile complete (cross-wave A reads follow)

    // ---- Phase 2: MFMA GEMM. Wave owns all 64 rows x cols [wave*64, wave*64+64).
    const int wc = wave*64;
    f32x4 acc[4][4];
    #pragma unroll
    for(int mf=0;mf<4;++mf)
        #pragma unroll
        for(int nf=0;nf<4;++nf)
            acc[mf][nf] = (f32x4){0.f,0.f,0.f,0.f};

    #pragma unroll
    for(int kc=0;kc<8;++kc){
        short8 bfv[4];
        #pragma unroll
        for(int nf=0;nf<4;++nf)
            bfv[nf] = *(const short8*)&wimgL[(size_t)kc*10240 + (wc+nf*16+l15)*40 + qq*8];
        short8 af[4];
        #pragma unroll
        for(int mf=0;mf<4;++mf)
            af[mf] = *(const short8*)&ytile[mf*16+l15][kc*32 + qq*8];
        #pragma unroll
        for(int nf=0;nf<4;++nf)
            #pragma unroll
            for(int mf=0;mf<4;++mf)
                acc[mf][nf] = __builtin_amdgcn_mfma_f32_16x16x32_bf16(af[mf], bfv[nf], acc[mf][nf], 0,0,0);
    }

    // ---- Phase 3: +b11, LN2 (cross-wave), gelu, residual, store.
    float b11c[4], g2c[4], b2c[4], wpc[4], bpc[4];
    #pragma unroll
    for(int nf=0;nf<4;++nf){
        const int col = wc + nf*16 + l15;
        b11c[nf]=b11[col]; g2c[nf]=g2[col]; b2c[nf]=b2[col];
        if(pre_mode){ wpc[nf]=w_pre[col]; bpc[nf]=b_pre[col]; }
    }
    #pragma unroll
    for(int mf=0;mf<4;++mf){
        #pragma unroll
        for(int rg=0;rg<4;++rg){
            float s=0.f, sq=0.f;
            #pragma unroll
            for(int nf=0;nf<4;++nf){
                const float v = acc[mf][nf][rg] + b11c[nf];
                s += v; sq = fmaf(v,v,sq);
            }
            #pragma unroll
            for(int o=1;o<16;o<<=1){ s += __shfl_xor(s,o,64); sq += __shfl_xor(sq,o,64); }
            if(l15==0){
                const int row = mf*16 + qq*4 + rg;
                redS[row][wave]=s; redQ[row][wave]=sq;
            }
        }
    }
    __syncthreads();
    if(tid < 64){
        const float s  = redS[tid][0]+redS[tid][1]+redS[tid][2]+redS[tid][3];
        const float q2 = redQ[tid][0]+redQ[tid][1]+redQ[tid][2]+redQ[tid][3];
        const float mean = s*(1.0f/FF);
        const float var  = fmaf(-mean, mean, q2*(1.0f/FF));
        stat[tid][0]=mean; stat[tid][1]=rsqrtf(var+1e-5f);
    }
    __syncthreads();
    #pragma unroll
    for(int mf=0;mf<4;++mf){
        #pragma unroll
        for(int rg=0;rg<4;++rg){
            const int row = mf*16 + qq*4 + rg;
            const float mean = stat[row][0], rs = stat[row][1];
            const size_t gbase = (size_t)(m0+row)*FF;
            float x0r = 0.0f;
            if(pre_mode) x0r = xsrc[(size_t)(m0+row)*2];
            #pragma unroll
            for(int nf=0;nf<4;++nf){
                const int col = wc + nf*16 + l15;
                const float v  = acc[mf][nf][rg] + b11c[nf];
                const float yn = fmaf((v-mean)*rs, g2c[nf], b2c[nf]);
                const float hres = pre_mode ? fmaf(x0r, wpc[nf], bpc[nf]) : hin[gbase+col];
                hout[gbase+col] = hres + gelu_exact(yn);
            }
        }
    }
}

// P[m][0..28] = ((h[m]*mask) @ w_proj + b_proj) * mask  (stride 32) — MFMA version.
// 64 rows/block; wave w: rows (w&1)*32..+31, cols (w>>1)*16..+15.
__global__ __launch_bounds__(256,4) void proj_kernel(
    const float* __restrict__ hin, const float* __restrict__ mask,
    const __hip_bfloat16* __restrict__ wpimg, const float* __restrict__ bproj,
    float* __restrict__ P)
{
    __shared__ __hip_bfloat16 ytile[64][264];
    const int tid = threadIdx.x;
    const int wave = tid>>6, lane = tid&63;
    const int l15 = lane&15, qq = lane>>4;
    const int m0 = blockIdx.x*64;
    const int f0 = lane*4;

    for(int rr=0; rr<16; ++rr){
        const int r = wave*16+rr;
        const int m = m0+r;
        const float mk = mask[m];
        const float4 hc = *(const float4*)&hin[(size_t)m*FF + f0];
        *(uint2*)&ytile[r][f0] = make_uint2(pack2bf(hc.x*mk, hc.y*mk), pack2bf(hc.z*mk, hc.w*mk));
    }
    __syncthreads();

    const int rh = (wave&1)*32, wc2 = (wave>>1)*16;
    f32x4 acc[2];
    acc[0] = (f32x4){0.f,0.f,0.f,0.f};
    acc[1] = (f32x4){0.f,0.f,0.f,0.f};
    #pragma unroll
    for(int kc=0;kc<8;++kc){
        const short8 bfv = *(const short8*)&wpimg[(size_t)kc*1280 + (wc2+l15)*40 + qq*8];
        #pragma unroll
        for(int mf=0;mf<2;++mf){
            const short8 af = *(const short8*)&ytile[rh+mf*16+l15][kc*32 + qq*8];
            acc[mf] = __builtin_amdgcn_mfma_f32_16x16x32_bf16(af, bfv, acc[mf], 0,0,0);
        }
    }
    const int col = wc2 + l15;
    const float bp = (col<PROJN)? bproj[col] : 0.0f;
    #pragma unroll
    for(int mf=0;mf<2;++mf){
        #pragma unroll
        for(int rg=0;rg<4;++rg){
            const int row = rh + mf*16 + qq*4 + rg;
            const float mk = mask[m0+row];
            P[(size_t)(m0+row)*32 + col] = (acc[mf][rg] + bp)*mk;
        }
    }
}

// Rational-quadratic spline per (b,t); writes xo and block-reduced logdet
__global__ __launch_bounds__(256) void spline_kernel(
    const float* __restrict__ P, const float* __restrict__ x,
    const float* __restrict__ mask, float* __restrict__ out,
    float* __restrict__ logdet)
{
    const int tid = threadIdx.x;
    const int m = blockIdx.x*256 + tid;
    float p[32];
    #pragma unroll
    for(int j=0;j<8;++j) ((float4*)p)[j] = ((const float4*)P)[(size_t)m*8+j];
    const float x0 = x[(size_t)m*2];
    const float x1 = x[(size_t)m*2+1];
    const float mk = mask[m];
    const float sc = 0.0625f;

    float cw[11], ch[11], d[11];
    {
        float mx=-1e30f;
        #pragma unroll
        for(int j=0;j<10;++j) mx = fmaxf(mx, p[j]);
        float e[10]; float se=0.f;
        #pragma unroll
        for(int j=0;j<10;++j){ e[j]=__expf((p[j]-mx)*sc); se+=e[j]; }
        const float inv = __fdividef(1.0f, se);
        float cum=0.f;
        cw[0]=-TBF;
        #pragma unroll
        for(int j=0;j<10;++j){ cum += fmaf(0.99f, e[j]*inv, 0.001f); cw[j+1]=fmaf(2.0f*TBF,cum,-TBF); }
        cw[10]=TBF;
    }
    {
        float mx=-1e30f;
        #pragma unroll
        for(int j=0;j<10;++j) mx = fmaxf(mx, p[10+j]);
        float e[10]; float se=0.f;
        #pragma unroll
        for(int j=0;j<10;++j){ e[j]=__expf((p[10+j]-mx)*sc); se+=e[j]; }
        const float inv = __fdividef(1.0f, se);
        float cum=0.f;
        ch[0]=-TBF;
        #pragma unroll
        for(int j=0;j<10;++j){ cum += fmaf(0.99f, e[j]*inv, 0.001f); ch[j+1]=fmaf(2.0f*TBF,cum,-TBF); }
        ch[10]=TBF;
    }
    d[0]=1.0f; d[10]=1.0f;
    #pragma unroll
    for(int k=1;k<10;++k) d[k] = 0.001f + softplusf_(p[19+k]);

    const bool inside = (x1>=-TBF)&&(x1<=TBF);
    const float xc = fminf(fmaxf(x1,-TBF),TBF);

    float icw=cw[0], ibw=cw[1]-cw[0], ich=ch[0], ibh=ch[1]-ch[0], dk=d[0], dk1=d[1];
    #pragma unroll
    for(int j=1;j<10;++j){
        const bool sel = (xc>=cw[j]);
        icw = sel? cw[j]      : icw;
        ibw = sel? cw[j+1]-cw[j] : ibw;
        ich = sel? ch[j]      : ich;
        ibh = sel? ch[j+1]-ch[j] : ibh;
        dk  = sel? d[j]       : dk;
        dk1 = sel? d[j+1]     : dk1;
    }

    const float delta = __fdividef(ibh, ibw);
    const float th = __fdividef(xc-icw, ibw);
    const float th1m = th*(1.0f-th);
    const float denom = fmaf(fmaf(-2.0f,delta,dk+dk1), th1m, delta);
    const float num = ibh*fmaf(delta*th, th, dk*th1m);
    const float yv = ich + __fdividef(num, denom);
    const float omt = 1.0f-th;
    const float dnum = delta*delta*(dk1*th*th + 2.0f*delta*th1m + dk*omt*omt);
    const float lad = __logf(dnum) - 2.0f*__logf(denom);
    const float y1 = inside? yv : x1;
    const float lv = inside? lad : 0.0f;

    out[(size_t)m*2]   = x0*mk;
    out[(size_t)m*2+1] = y1*mk;

    __shared__ float red[256];
    red[tid]=lv*mk;
    __syncthreads();
    #pragma unroll
    for(int s=128;s>0;s>>=1){ if(tid<s) red[tid]+=red[tid+s]; __syncthreads(); }
    if(tid==0) atomicAdd(&logdet[blockIdx.x>>5], red[0]);
}

extern "C" void kernel_launch(void* const* d_in, const int* in_sizes, int n_in,
                              void* d_out, int out_size, void* d_ws, size_t ws_size,
                              hipStream_t stream)
{
    const float* x      = (const float*)d_in[0];
    const float* mask   = (const float*)d_in[1];
    const float* w_pre  = (const float*)d_in[2];
    const float* b_pre  = (const float*)d_in[3];
    const float* dw_k   = (const float*)d_in[4];
    const float* dw_b   = (const float*)d_in[5];
    const float* w11    = (const float*)d_in[6];
    const float* b11    = (const float*)d_in[7];
    const float* ln1g   = (const float*)d_in[8];
    const float* ln1b   = (const float*)d_in[9];
    const float* ln2g   = (const float*)d_in[10];
    const float* ln2b   = (const float*)d_in[11];
    const float* w_proj = (const float*)d_in[12];
    const float* b_proj = (const float*)d_in[13];

    const size_t hbytes = (size_t)MM*FF*4;          // 128 MiB
    float* h0 = (float*)d_ws;
    float* h1 = h0 + (size_t)MM*FF;
    float* P  = h0;                                  // overlay after layers are done
    float* outp   = (float*)d_out;
    float* logdet = outp + (size_t)MM*2;

    // bf16 weight images: 3 layer images (3x160 KiB) + proj image (20 KiB).
    // Prefer ws tail; else overlay d_out (fully rewritten by spline afterwards).
    __hip_bfloat16* wimg;
    if(ws_size >= 2*hbytes + 3*163840 + 20480)
        wimg = (__hip_bfloat16*)((char*)d_ws + 2*hbytes);
    else
        wimg = (__hip_bfloat16*)d_out;
    __hip_bfloat16* wpimg = wimg + (size_t)3*81920;

    wprep_kernel<<<32, 256, 0, stream>>>(w11, w_proj, wimg, wpimg);

    // layer 0 fuses the rank-1 pre-expansion (reads x directly); ping-pong after.
    // dil = 1, 3, 9
    layer_kernel<<<MM/64, 256, 0, stream>>>(
        (const float*)nullptr, h1, x, w_pre, b_pre, mask,
        dw_k, dw_b, ln1g, ln1b, wimg, b11, ln2g, ln2b, 1, 1);
    layer_kernel<<<MM/64, 256, 0, stream>>>(
        h1, h0, x, w_pre, b_pre, mask,
        dw_k + (size_t)3*FF, dw_b + (size_t)FF,
        ln1g + (size_t)FF, ln1b + (size_t)FF,
        wimg + (size_t)81920, b11 + (size_t)FF,
        ln2g + (size_t)FF, ln2b + (size_t)FF, 3, 0);
    layer_kernel<<<MM/64, 256, 0, stream>>>(
        h0, h1, x, w_pre, b_pre, mask,
        dw_k + (size_t)6*FF, dw_b + (size_t)2*FF,
        ln1g + (size_t)2*FF, ln1b + (size_t)2*FF,
        wimg + (size_t)2*81920, b11 + (size_t)2*FF,
        ln2g + (size_t)2*FF, ln2b + (size_t)2*FF, 9, 0);

    proj_kernel<<<MM/64, 256, 0, stream>>>(h1, mask, wpimg, b_proj, P);

    hipMemsetAsync(logdet, 0, BB*sizeof(float), stream);
    spline_kernel<<<MM/256, 256, 0, stream>>>(P, x, mask, outp, logdet);
}

// Round 7
// 476.641 us; speedup vs baseline: 6.3652x; 1.0162x over previous
//
#include <hip/hip_runtime.h>
#include <hip/hip_bf16.h>
#include <cmath>

#define BB 16
#define TT 8192
#define MM (BB*TT)
#define FF 256
#define TBF 5.0f
#define PROJN 29

typedef __attribute__((ext_vector_type(8))) short short8;
typedef __attribute__((ext_vector_type(4))) float f32x4;

// Branch-free erf (Abramowitz-Stegun 7.1.26, max abs err 1.5e-7).
__device__ __forceinline__ float gelu_exact(float x){
    const float z  = x*0.70710678118654752440f;
    const float az = fabsf(z);
    const float t  = __builtin_amdgcn_rcpf(fmaf(0.3275911f, az, 1.0f));
    float p = fmaf(1.061405429f, t, -1.453152027f);
    p = fmaf(p, t, 1.421413741f);
    p = fmaf(p, t, -0.284496736f);
    p = fmaf(p, t, 0.254829592f);
    p = p*t;
    const float e  = __expf(-az*az);
    const float r  = fmaf(-p, e, 1.0f);          // erf(|z|)
    const float er = copysignf(r, z);            // erf(z)
    return 0.5f*x*(1.0f + er);
}
__device__ __forceinline__ float softplusf_(float v){
    return fmaxf(v,0.0f) + log1pf(__expf(-fabsf(v)));
}
__device__ __forceinline__ unsigned pack2bf(float a, float b){
    __hip_bfloat16 ha = __float2bfloat16(a);
    __hip_bfloat16 hb = __float2bfloat16(b);
    const unsigned ua = *reinterpret_cast<const unsigned short*>(&ha);
    const unsigned ub = *reinterpret_cast<const unsigned short*>(&hb);
    return ua | (ub<<16);
}

// Layer images: wimg[layer][kc][n][40] bf16, [n][kp] = w11[kc*32+kp][n] (kp<32; pad 0).
// Proj image (blocks 24..31): wpimg[kc][n 0..31][40], [n][kp] = wproj[kc*32+kp][n] (n<29; pad 0).
__global__ __launch_bounds__(256) void wprep_kernel(
    const float* __restrict__ w11, const float* __restrict__ wproj,
    __hip_bfloat16* __restrict__ wimg, __hip_bfloat16* __restrict__ wpimg)
{
    if(blockIdx.x < 24){
        const int layer = blockIdx.x>>3, kc = blockIdx.x&7;
        const float* __restrict__ w = w11 + (size_t)layer*FF*FF;
        __hip_bfloat16* __restrict__ o = wimg + (size_t)layer*81920 + kc*10240;
        for(int i=threadIdx.x; i<10240; i+=256){
            const int n = i/40, kp = i - n*40;
            const float v = (kp<32) ? w[(size_t)(kc*32+kp)*FF + n] : 0.0f;
            o[i] = __float2bfloat16(v);
        }
    } else {
        const int kc = blockIdx.x - 24;
        __hip_bfloat16* __restrict__ o = wpimg + (size_t)kc*1280;
        for(int i=threadIdx.x; i<1280; i+=256){
            const int n = i/40, kp = i - n*40;
            const float v = (kp<32 && n<PROJN) ? wproj[(size_t)(kc*32+kp)*PROJN + n] : 0.0f;
            o[i] = __float2bfloat16(v);
        }
    }
}

// One layer, 64 rows x 256 cols per block, 4 waves, bf16 MFMA 16x16x32.
// B-fragments read straight from L2-resident wimg (no LDS staging).
// pre_mode: layer-0 input h = x0*w_pre + b_pre computed on the fly (rank-1).
__global__ __launch_bounds__(256,4) void layer_kernel(
    const float* __restrict__ hin, float* __restrict__ hout,
    const float* __restrict__ xsrc,
    const float* __restrict__ w_pre, const float* __restrict__ b_pre,
    const float* __restrict__ mask,
    const float* __restrict__ dwk, const float* __restrict__ dwb,
    const float* __restrict__ g1, const float* __restrict__ b1,
    const __hip_bfloat16* __restrict__ wimgL, const float* __restrict__ b11,
    const float* __restrict__ g2, const float* __restrict__ b2,
    const int dil, const int pre_mode)
{
    __shared__ __hip_bfloat16 ytile[64][264];     // +8 bf16 pad
    __shared__ float redS[64][4];
    __shared__ float redQ[64][4];
    __shared__ float stat[64][2];

    const int tid  = threadIdx.x;
    const int wave = tid>>6, lane = tid&63;
    const int l15  = lane&15, qq = lane>>4;

    int bid = blockIdx.x;                          // XCD-bijective swizzle (2048%8==0)
    bid = (bid&7)*((int)gridDim.x>>3) + (bid>>3);
    const int m0 = bid*64;
    const int b  = m0/TT;
    const int t0 = m0 - b*TT;
    const float* __restrict__ mrow = mask + (size_t)b*TT;

    // ---- Phase 1: conv + LN1 + gelu -> ytile (bf16). Wave handles rows wave*16..+15.
    const int f0 = lane*4;
    const float4 k0 = *(const float4*)&dwk[f0];
    const float4 k1 = *(const float4*)&dwk[FF+f0];
    const float4 k2 = *(const float4*)&dwk[2*FF+f0];
    const float4 cb = *(const float4*)&dwb[f0];
    const float4 g1v= *(const float4*)&g1[f0];
    const float4 b1v= *(const float4*)&b1[f0];
    float4 wp4, bp4;
    if(pre_mode){ wp4 = *(const float4*)&w_pre[f0]; bp4 = *(const float4*)&b_pre[f0]; }

    #pragma unroll 4
    for(int rr=0; rr<16; ++rr){
        const int r = wave*16+rr;
        const int m = m0+r, t = t0+r;
        // branchless boundary: clamped addresses + zeroed mask taps
        const int okl = (t>=dil)    ? 1 : 0;
        const int okr = (t+dil<TT)  ? 1 : 0;
        const int ml  = m - dil*okl;
        const int mr  = m + dil*okr;
        const float mkc = mrow[t];
        const float mkl = mrow[t - dil*okl] * (float)okl;
        const float mkr = mrow[t + dil*okr] * (float)okr;
        float4 hc, hl, hr;
        if(pre_mode){
            const float xc_ = xsrc[(size_t)m *2];
            const float xl_ = xsrc[(size_t)ml*2];
            const float xr_ = xsrc[(size_t)mr*2];
            hc.x=fmaf(xc_,wp4.x,bp4.x); hc.y=fmaf(xc_,wp4.y,bp4.y);
            hc.z=fmaf(xc_,wp4.z,bp4.z); hc.w=fmaf(xc_,wp4.w,bp4.w);
            hl.x=fmaf(xl_,wp4.x,bp4.x); hl.y=fmaf(xl_,wp4.y,bp4.y);
            hl.z=fmaf(xl_,wp4.z,bp4.z); hl.w=fmaf(xl_,wp4.w,bp4.w);
            hr.x=fmaf(xr_,wp4.x,bp4.x); hr.y=fmaf(xr_,wp4.y,bp4.y);
            hr.z=fmaf(xr_,wp4.z,bp4.z); hr.w=fmaf(xr_,wp4.w,bp4.w);
        } else {
            hc = *(const float4*)&hin[(size_t)m *FF + f0];
            hl = *(const float4*)&hin[(size_t)ml*FF + f0];
            hr = *(const float4*)&hin[(size_t)mr*FF + f0];
        }
        float4 a;
        a.x = fmaf(hc.x*mkc, k1.x, cb.x);
        a.y = fmaf(hc.y*mkc, k1.y, cb.y);
        a.z = fmaf(hc.z*mkc, k1.z, cb.z);
        a.w = fmaf(hc.w*mkc, k1.w, cb.w);
        a.x = fmaf(hl.x*mkl, k0.x, a.x);
        a.y = fmaf(hl.y*mkl, k0.y, a.y);
        a.z = fmaf(hl.z*mkl, k0.z, a.z);
        a.w = fmaf(hl.w*mkl, k0.w, a.w);
        a.x = fmaf(hr.x*mkr, k2.x, a.x);
        a.y = fmaf(hr.y*mkr, k2.y, a.y);
        a.z = fmaf(hr.z*mkr, k2.z, a.z);
        a.w = fmaf(hr.w*mkr, k2.w, a.w);
        // single-pass LN1: sum and sum-of-squares reduced together (ILP)
        float s  = a.x+a.y+a.z+a.w;
        float sq = fmaf(a.x,a.x, fmaf(a.y,a.y, fmaf(a.z,a.z, a.w*a.w)));
        #pragma unroll
        for(int o=32;o>0;o>>=1){
            s  += __shfl_xor(s,o,64);
            sq += __shfl_xor(sq,o,64);
        }
        const float mean = s*(1.0f/FF);
        const float var  = fmaf(-mean, mean, sq*(1.0f/FF));
        const float rs = rsqrtf(var + 1e-5f);
        const float y0 = gelu_exact(fmaf((a.x-mean)*rs, g1v.x, b1v.x));
        const float y1 = gelu_exact(fmaf((a.y-mean)*rs, g1v.y, b1v.y));
        const float y2 = gelu_exact(fmaf((a.z-mean)*rs, g1v.z, b1v.z));
        const float y3 = gelu_exact(fmaf((a.w-mean)*rs, g1v.w, b1v.w));
        *(uint2*)&ytile[r][f0] = make_uint2(pack2bf(y0,y1), pack2bf(y2,y3));
    }

    __syncthreads();   // ytile complete (cross-wave A reads follow)

    // ---- Phase 2: MFMA GEMM. Wave owns all 64 rows x cols [wave*64, wave*64+64).
    const int wc = wave*64;
    f32x4 acc[4][4];
    #pragma unroll
    for(int mf=0;mf<4;++mf)
        #pragma unroll
        for(int nf=0;nf<4;++nf)
            acc[mf][nf] = (f32x4){0.f,0.f,0.f,0.f};

    #pragma unroll
    for(int kc=0;kc<8;++kc){
        short8 bfv[4];
        #pragma unroll
        for(int nf=0;nf<4;++nf)
            bfv[nf] = *(const short8*)&wimgL[(size_t)kc*10240 + (wc+nf*16+l15)*40 + qq*8];
        short8 af[4];
        #pragma unroll
        for(int mf=0;mf<4;++mf)
            af[mf] = *(const short8*)&ytile[mf*16+l15][kc*32 + qq*8];
        #pragma unroll
        for(int nf=0;nf<4;++nf)
            #pragma unroll
            for(int mf=0;mf<4;++mf)
                acc[mf][nf] = __builtin_amdgcn_mfma_f32_16x16x32_bf16(af[mf], bfv[nf], acc[mf][nf], 0,0,0);
    }

    // ---- Phase 3: +b11, LN2 (cross-wave), gelu, residual (2-deep prefetch), store.
    float b11c[4], g2c[4], b2c[4], wpc[4], bpc[4];
    #pragma unroll
    for(int nf=0;nf<4;++nf){
        const int col = wc + nf*16 + l15;
        b11c[nf]=b11[col]; g2c[nf]=g2[col]; b2c[nf]=b2[col];
        if(pre_mode){ wpc[nf]=w_pre[col]; bpc[nf]=b_pre[col]; }
    }
    #pragma unroll
    for(int mf=0;mf<4;++mf){
        #pragma unroll
        for(int rg=0;rg<4;++rg){
            float s=0.f, sq=0.f;
            #pragma unroll
            for(int nf=0;nf<4;++nf){
                const float v = acc[mf][nf][rg] + b11c[nf];
                s += v; sq = fmaf(v,v,sq);
            }
            #pragma unroll
            for(int o=1;o<16;o<<=1){ s += __shfl_xor(s,o,64); sq += __shfl_xor(sq,o,64); }
            if(l15==0){
                const int row = mf*16 + qq*4 + rg;
                redS[row][wave]=s; redQ[row][wave]=sq;
            }
        }
    }
    __syncthreads();
    if(tid < 64){
        const float s  = redS[tid][0]+redS[tid][1]+redS[tid][2]+redS[tid][3];
        const float q2 = redQ[tid][0]+redQ[tid][1]+redQ[tid][2]+redQ[tid][3];
        const float mean = s*(1.0f/FF);
        const float var  = fmaf(-mean, mean, q2*(1.0f/FF));
        stat[tid][0]=mean; stat[tid][1]=rsqrtf(var+1e-5f);
    }
    __syncthreads();

    // residual prefetch macro: 16 values for row-group mf into dst[16]
    #define LOAD_RES(mf_, dst) do{ \
        if(pre_mode){ \
            _Pragma("unroll") \
            for(int rg=0;rg<4;++rg){ \
                const float x0r = xsrc[(size_t)(m0+(mf_)*16+qq*4+rg)*2]; \
                _Pragma("unroll") \
                for(int nf=0;nf<4;++nf) (dst)[rg*4+nf] = fmaf(x0r, wpc[nf], bpc[nf]); \
            } \
        } else { \
            _Pragma("unroll") \
            for(int rg=0;rg<4;++rg){ \
                const size_t gb = (size_t)(m0+(mf_)*16+qq*4+rg)*FF; \
                _Pragma("unroll") \
                for(int nf=0;nf<4;++nf) (dst)[rg*4+nf] = hin[gb + wc+nf*16+l15]; \
            } \
        } }while(0)
    #define STORE_MF(mf_, src) do{ \
        _Pragma("unroll") \
        for(int rg=0;rg<4;++rg){ \
            const int row = (mf_)*16 + qq*4 + rg; \
            const float mean = stat[row][0], rs = stat[row][1]; \
            const size_t gb = (size_t)(m0+row)*FF; \
            _Pragma("unroll") \
            for(int nf=0;nf<4;++nf){ \
                const int col = wc + nf*16 + l15; \
                const float v  = acc[(mf_)][nf][rg] + b11c[nf]; \
                const float yn = fmaf((v-mean)*rs, g2c[nf], b2c[nf]); \
                hout[gb+col] = (src)[rg*4+nf] + gelu_exact(yn); \
            } \
        } }while(0)

    float hrA[16], hrB[16];
    LOAD_RES(0, hrA);
    LOAD_RES(1, hrB);
    STORE_MF(0, hrA);
    LOAD_RES(2, hrA);
    STORE_MF(1, hrB);
    LOAD_RES(3, hrB);
    STORE_MF(2, hrA);
    STORE_MF(3, hrB);
    #undef LOAD_RES
    #undef STORE_MF
}

// P[m][0..28] = ((h[m]*mask) @ w_proj + b_proj) * mask  (stride 32) — MFMA version.
// 64 rows/block; wave w: rows (w&1)*32..+31, cols (w>>1)*16..+15.
__global__ __launch_bounds__(256,4) void proj_kernel(
    const float* __restrict__ hin, const float* __restrict__ mask,
    const __hip_bfloat16* __restrict__ wpimg, const float* __restrict__ bproj,
    float* __restrict__ P)
{
    __shared__ __hip_bfloat16 ytile[64][264];
    const int tid = threadIdx.x;
    const int wave = tid>>6, lane = tid&63;
    const int l15 = lane&15, qq = lane>>4;
    const int m0 = blockIdx.x*64;
    const int f0 = lane*4;

    #pragma unroll 4
    for(int rr=0; rr<16; ++rr){
        const int r = wave*16+rr;
        const int m = m0+r;
        const float mk = mask[m];
        const float4 hc = *(const float4*)&hin[(size_t)m*FF + f0];
        *(uint2*)&ytile[r][f0] = make_uint2(pack2bf(hc.x*mk, hc.y*mk), pack2bf(hc.z*mk, hc.w*mk));
    }
    __syncthreads();

    const int rh = (wave&1)*32, wc2 = (wave>>1)*16;
    f32x4 acc[2];
    acc[0] = (f32x4){0.f,0.f,0.f,0.f};
    acc[1] = (f32x4){0.f,0.f,0.f,0.f};
    #pragma unroll
    for(int kc=0;kc<8;++kc){
        const short8 bfv = *(const short8*)&wpimg[(size_t)kc*1280 + (wc2+l15)*40 + qq*8];
        #pragma unroll
        for(int mf=0;mf<2;++mf){
            const short8 af = *(const short8*)&ytile[rh+mf*16+l15][kc*32 + qq*8];
            acc[mf] = __builtin_amdgcn_mfma_f32_16x16x32_bf16(af, bfv, acc[mf], 0,0,0);
        }
    }
    const int col = wc2 + l15;
    const float bp = (col<PROJN)? bproj[col] : 0.0f;
    #pragma unroll
    for(int mf=0;mf<2;++mf){
        #pragma unroll
        for(int rg=0;rg<4;++rg){
            const int row = rh + mf*16 + qq*4 + rg;
            const float mk = mask[m0+row];
            P[(size_t)(m0+row)*32 + col] = (acc[mf][rg] + bp)*mk;
        }
    }
}

// Rational-quadratic spline per (b,t); writes xo and block-reduced logdet
__global__ __launch_bounds__(256) void spline_kernel(
    const float* __restrict__ P, const float* __restrict__ x,
    const float* __restrict__ mask, float* __restrict__ out,
    float* __restrict__ logdet)
{
    const int tid = threadIdx.x;
    const int m = blockIdx.x*256 + tid;
    float p[32];
    #pragma unroll
    for(int j=0;j<8;++j) ((float4*)p)[j] = ((const float4*)P)[(size_t)m*8+j];
    const float x0 = x[(size_t)m*2];
    const float x1 = x[(size_t)m*2+1];
    const float mk = mask[m];
    const float sc = 0.0625f;

    float cw[11], ch[11], d[11];
    {
        float mx=-1e30f;
        #pragma unroll
        for(int j=0;j<10;++j) mx = fmaxf(mx, p[j]);
        float e[10]; float se=0.f;
        #pragma unroll
        for(int j=0;j<10;++j){ e[j]=__expf((p[j]-mx)*sc); se+=e[j]; }
        const float inv = __fdividef(1.0f, se);
        float cum=0.f;
        cw[0]=-TBF;
        #pragma unroll
        for(int j=0;j<10;++j){ cum += fmaf(0.99f, e[j]*inv, 0.001f); cw[j+1]=fmaf(2.0f*TBF,cum,-TBF); }
        cw[10]=TBF;
    }
    {
        float mx=-1e30f;
        #pragma unroll
        for(int j=0;j<10;++j) mx = fmaxf(mx, p[10+j]);
        float e[10]; float se=0.f;
        #pragma unroll
        for(int j=0;j<10;++j){ e[j]=__expf((p[10+j]-mx)*sc); se+=e[j]; }
        const float inv = __fdividef(1.0f, se);
        float cum=0.f;
        ch[0]=-TBF;
        #pragma unroll
        for(int j=0;j<10;++j){ cum += fmaf(0.99f, e[j]*inv, 0.001f); ch[j+1]=fmaf(2.0f*TBF,cum,-TBF); }
        ch[10]=TBF;
    }
    d[0]=1.0f; d[10]=1.0f;
    #pragma unroll
    for(int k=1;k<10;++k) d[k] = 0.001f + softplusf_(p[19+k]);

    const bool inside = (x1>=-TBF)&&(x1<=TBF);
    const float xc = fminf(fmaxf(x1,-TBF),TBF);

    float icw=cw[0], ibw=cw[1]-cw[0], ich=ch[0], ibh=ch[1]-ch[0], dk=d[0], dk1=d[1];
    #pragma unroll
    for(int j=1;j<10;++j){
        const bool sel = (xc>=cw[j]);
        icw = sel? cw[j]      : icw;
        ibw = sel? cw[j+1]-cw[j] : ibw;
        ich = sel? ch[j]      : ich;
        ibh = sel? ch[j+1]-ch[j] : ibh;
        dk  = sel? d[j]       : dk;
        dk1 = sel? d[j+1]     : dk1;
    }

    const float delta = __fdividef(ibh, ibw);
    const float th = __fdividef(xc-icw, ibw);
    const float th1m = th*(1.0f-th);
    const float denom = fmaf(fmaf(-2.0f,delta,dk+dk1), th1m, delta);
    const float num = ibh*fmaf(delta*th, th, dk*th1m);
    const float yv = ich + __fdividef(num, denom);
    const float omt = 1.0f-th;
    const float dnum = delta*delta*(dk1*th*th + 2.0f*delta*th1m + dk*omt*omt);
    const float lad = __logf(dnum) - 2.0f*__logf(denom);
    const float y1 = inside? yv : x1;
    const float lv = inside? lad : 0.0f;

    out[(size_t)m*2]   = x0*mk;
    out[(size_t)m*2+1] = y1*mk;

    __shared__ float red[256];
    red[tid]=lv*mk;
    __syncthreads();
    #pragma unroll
    for(int s=128;s>0;s>>=1){ if(tid<s) red[tid]+=red[tid+s]; __syncthreads(); }
    if(tid==0) atomicAdd(&logdet[blockIdx.x>>5], red[0]);
}

extern "C" void kernel_launch(void* const* d_in, const int* in_sizes, int n_in,
                              void* d_out, int out_size, void* d_ws, size_t ws_size,
                              hipStream_t stream)
{
    const float* x      = (const float*)d_in[0];
    const float* mask   = (const float*)d_in[1];
    const float* w_pre  = (const float*)d_in[2];
    const float* b_pre  = (const float*)d_in[3];
    const float* dw_k   = (const float*)d_in[4];
    const float* dw_b   = (const float*)d_in[5];
    const float* w11    = (const float*)d_in[6];
    const float* b11    = (const float*)d_in[7];
    const float* ln1g   = (const float*)d_in[8];
    const float* ln1b   = (const float*)d_in[9];
    const float* ln2g   = (const float*)d_in[10];
    const float* ln2b   = (const float*)d_in[11];
    const float* w_proj = (const float*)d_in[12];
    const float* b_proj = (const float*)d_in[13];

    const size_t hbytes = (size_t)MM*FF*4;          // 128 MiB
    float* h0 = (float*)d_ws;
    float* h1 = h0 + (size_t)MM*FF;
    float* P  = h0;                                  // overlay after layers are done
    float* outp   = (float*)d_out;
    float* logdet = outp + (size_t)MM*2;

    // bf16 weight images: 3 layer images (3x160 KiB) + proj image (20 KiB).
    __hip_bfloat16* wimg;
    if(ws_size >= 2*hbytes + 3*163840 + 20480)
        wimg = (__hip_bfloat16*)((char*)d_ws + 2*hbytes);
    else
        wimg = (__hip_bfloat16*)d_out;
    __hip_bfloat16* wpimg = wimg + (size_t)3*81920;

    wprep_kernel<<<32, 256, 0, stream>>>(w11, w_proj, wimg, wpimg);

    // layer 0 fuses the rank-1 pre-expansion (reads x directly); ping-pong after.
    // dil = 1, 3, 9
    layer_kernel<<<MM/64, 256, 0, stream>>>(
        (const float*)nullptr, h1, x, w_pre, b_pre, mask,
        dw_k, dw_b, ln1g, ln1b, wimg, b11, ln2g, ln2b, 1, 1);
    layer_kernel<<<MM/64, 256, 0, stream>>>(
        h1, h0, x, w_pre, b_pre, mask,
        dw_k + (size_t)3*FF, dw_b + (size_t)FF,
        ln1g + (size_t)FF, ln1b + (size_t)FF,
        wimg + (size_t)81920, b11 + (size_t)FF,
        ln2g + (size_t)FF, ln2b + (size_t)FF, 3, 0);
    layer_kernel<<<MM/64, 256, 0, stream>>>(
        h0, h1, x, w_pre, b_pre, mask,
        dw_k + (size_t)6*FF, dw_b + (size_t)2*FF,
        ln1g + (size_t)2*FF, ln1b + (size_t)2*FF,
        wimg + (size_t)2*81920, b11 + (size_t)2*FF,
        ln2g + (size_t)2*FF, ln2b + (size_t)2*FF, 9, 0);

    proj_kernel<<<MM/64, 256, 0, stream>>>(h1, mask, wpimg, b_proj, P);

    hipMemsetAsync(logdet, 0, BB*sizeof(float), stream);
    spline_kernel<<<MM/256, 256, 0, stream>>>(P, x, mask, outp, logdet);
}

// Round 8
// 354.502 us; speedup vs baseline: 8.5582x; 1.3445x over previous
//
#include <hip/hip_runtime.h>
#include <hip/hip_bf16.h>
#include <cmath>

#define BB 16
#define TT 8192
#define MM (BB*TT)
#define FF 256
#define TBF 5.0f
#define PROJN 29

typedef __attribute__((ext_vector_type(8))) short short8;
typedef __attribute__((ext_vector_type(4))) float f32x4;

// Branch-free erf (Abramowitz-Stegun 7.1.26, max abs err 1.5e-7).
__device__ __forceinline__ float gelu_exact(float x){
    const float z  = x*0.70710678118654752440f;
    const float az = fabsf(z);
    const float t  = __builtin_amdgcn_rcpf(fmaf(0.3275911f, az, 1.0f));
    float p = fmaf(1.061405429f, t, -1.453152027f);
    p = fmaf(p, t, 1.421413741f);
    p = fmaf(p, t, -0.284496736f);
    p = fmaf(p, t, 0.254829592f);
    p = p*t;
    const float e  = __expf(-az*az);
    const float r  = fmaf(-p, e, 1.0f);
    return 0.5f*x*(1.0f + copysignf(r, z));
}
__device__ __forceinline__ float softplusf_(float v){
    return fmaxf(v,0.0f) + log1pf(__expf(-fabsf(v)));
}
__device__ __forceinline__ unsigned pack2bf(float a, float b){
    __hip_bfloat16 ha = __float2bfloat16(a);
    __hip_bfloat16 hb = __float2bfloat16(b);
    const unsigned ua = *reinterpret_cast<const unsigned short*>(&ha);
    const unsigned ub = *reinterpret_cast<const unsigned short*>(&hb);
    return ua | (ub<<16);
}
__device__ __forceinline__ float bf2f(unsigned short u){
    unsigned v = ((unsigned)u)<<16;
    return *reinterpret_cast<float*>(&v);
}
__device__ __forceinline__ float4 unpack4(uint2 q){
    float4 f;
    f.x = bf2f((unsigned short)(q.x&0xffff)); f.y = bf2f((unsigned short)(q.x>>16));
    f.z = bf2f((unsigned short)(q.y&0xffff)); f.w = bf2f((unsigned short)(q.y>>16));
    return f;
}

// Layer images: wimg[layer][kc][n][40] bf16, [n][kp] = w11[kc*32+kp][n] (kp<32; pad 0).
// Proj image (blocks 24..31): wpimg[kc][n 0..31][40].
__global__ __launch_bounds__(256) void wprep_kernel(
    const float* __restrict__ w11, const float* __restrict__ wproj,
    __hip_bfloat16* __restrict__ wimg, __hip_bfloat16* __restrict__ wpimg)
{
    if(blockIdx.x < 24){
        const int layer = blockIdx.x>>3, kc = blockIdx.x&7;
        const float* __restrict__ w = w11 + (size_t)layer*FF*FF;
        __hip_bfloat16* __restrict__ o = wimg + (size_t)layer*81920 + kc*10240;
        for(int i=threadIdx.x; i<10240; i+=256){
            const int n = i/40, kp = i - n*40;
            const float v = (kp<32) ? w[(size_t)(kc*32+kp)*FF + n] : 0.0f;
            o[i] = __float2bfloat16(v);
        }
    } else {
        const int kc = blockIdx.x - 24;
        __hip_bfloat16* __restrict__ o = wpimg + (size_t)kc*1280;
        for(int i=threadIdx.x; i<1280; i+=256){
            const int n = i/40, kp = i - n*40;
            const float v = (kp<32 && n<PROJN) ? wproj[(size_t)(kc*32+kp)*PROJN + n] : 0.0f;
            o[i] = __float2bfloat16(v);
        }
    }
}

// One layer, 32 rows x 256 cols per block, 4 waves, bf16 MFMA 16x16x32.
// h stored bf16 between layers; residual via LDS hstash (no global re-read).
// pre_mode: layer-0 input h = x0*w_pre + b_pre computed on the fly (rank-1).
__global__ __launch_bounds__(256,4) void layer_kernel(
    const __hip_bfloat16* __restrict__ hbin, __hip_bfloat16* __restrict__ hbout,
    const float* __restrict__ xsrc,
    const float* __restrict__ w_pre, const float* __restrict__ b_pre,
    const float* __restrict__ mask,
    const float* __restrict__ dwk, const float* __restrict__ dwb,
    const float* __restrict__ g1, const float* __restrict__ b1,
    const __hip_bfloat16* __restrict__ wimgL, const float* __restrict__ b11,
    const float* __restrict__ g2, const float* __restrict__ b2,
    const int dil, const int pre_mode)
{
    __shared__ __hip_bfloat16 ytile[32][264];   // GEMM A staging
    __shared__ __hip_bfloat16 hstash[32][268];  // center h for residual (bank-staggered)
    __shared__ float redS[32][4];
    __shared__ float redQ[32][4];
    __shared__ float stat[32][2];

    const int tid  = threadIdx.x;
    const int wave = tid>>6, lane = tid&63;
    const int l15  = lane&15, qq = lane>>4;

    int bid = blockIdx.x;                        // XCD swizzle (4096%8==0); keeps
    bid = (bid&7)*((int)gridDim.x>>3) + (bid>>3);// adjacent tiles on one XCD (halo L2)
    const int m0 = bid*32;
    const int b  = m0/TT;
    const int t0 = m0 - b*TT;
    const float* __restrict__ mrow = mask + (size_t)b*TT;

    // ---- Phase 1: conv + LN1 + gelu -> ytile; stash center h -> hstash.
    const int f0 = lane*4;
    const float4 k0 = *(const float4*)&dwk[f0];
    const float4 k1 = *(const float4*)&dwk[FF+f0];
    const float4 k2 = *(const float4*)&dwk[2*FF+f0];
    const float4 cb = *(const float4*)&dwb[f0];
    const float4 g1v= *(const float4*)&g1[f0];
    const float4 b1v= *(const float4*)&b1[f0];
    float4 wp4, bp4;
    if(pre_mode){ wp4 = *(const float4*)&w_pre[f0]; bp4 = *(const float4*)&b_pre[f0]; }

    #pragma unroll 4
    for(int rr=0; rr<8; ++rr){
        const int r = wave*8+rr;
        const int m = m0+r, t = t0+r;
        const int okl = (t>=dil)   ? 1 : 0;
        const int okr = (t+dil<TT) ? 1 : 0;
        const int ml  = m - dil*okl;
        const int mr  = m + dil*okr;
        const float mkc = mrow[t];
        const float mkl = mrow[t - dil*okl] * (float)okl;
        const float mkr = mrow[t + dil*okr] * (float)okr;
        float4 hc, hl, hr;
        uint2 hcraw;
        if(pre_mode){
            const float xc_ = xsrc[(size_t)m *2];
            const float xl_ = xsrc[(size_t)ml*2];
            const float xr_ = xsrc[(size_t)mr*2];
            hc.x=fmaf(xc_,wp4.x,bp4.x); hc.y=fmaf(xc_,wp4.y,bp4.y);
            hc.z=fmaf(xc_,wp4.z,bp4.z); hc.w=fmaf(xc_,wp4.w,bp4.w);
            hl.x=fmaf(xl_,wp4.x,bp4.x); hl.y=fmaf(xl_,wp4.y,bp4.y);
            hl.z=fmaf(xl_,wp4.z,bp4.z); hl.w=fmaf(xl_,wp4.w,bp4.w);
            hr.x=fmaf(xr_,wp4.x,bp4.x); hr.y=fmaf(xr_,wp4.y,bp4.y);
            hr.z=fmaf(xr_,wp4.z,bp4.z); hr.w=fmaf(xr_,wp4.w,bp4.w);
            hcraw = make_uint2(pack2bf(hc.x,hc.y), pack2bf(hc.z,hc.w));
        } else {
            hcraw          = *(const uint2*)&hbin[(size_t)m *FF + f0];
            const uint2 ql = *(const uint2*)&hbin[(size_t)ml*FF + f0];
            const uint2 qr = *(const uint2*)&hbin[(size_t)mr*FF + f0];
            hc = unpack4(hcraw); hl = unpack4(ql); hr = unpack4(qr);
        }
        *(uint2*)&hstash[r][f0] = hcraw;
        float4 a;
        a.x = fmaf(hc.x*mkc, k1.x, cb.x);
        a.y = fmaf(hc.y*mkc, k1.y, cb.y);
        a.z = fmaf(hc.z*mkc, k1.z, cb.z);
        a.w = fmaf(hc.w*mkc, k1.w, cb.w);
        a.x = fmaf(hl.x*mkl, k0.x, a.x);
        a.y = fmaf(hl.y*mkl, k0.y, a.y);
        a.z = fmaf(hl.z*mkl, k0.z, a.z);
        a.w = fmaf(hl.w*mkl, k0.w, a.w);
        a.x = fmaf(hr.x*mkr, k2.x, a.x);
        a.y = fmaf(hr.y*mkr, k2.y, a.y);
        a.z = fmaf(hr.z*mkr, k2.z, a.z);
        a.w = fmaf(hr.w*mkr, k2.w, a.w);
        float s  = a.x+a.y+a.z+a.w;
        float sq = fmaf(a.x,a.x, fmaf(a.y,a.y, fmaf(a.z,a.z, a.w*a.w)));
        #pragma unroll
        for(int o=32;o>0;o>>=1){
            s  += __shfl_xor(s,o,64);
            sq += __shfl_xor(sq,o,64);
        }
        const float mean = s*(1.0f/FF);
        const float var  = fmaf(-mean, mean, sq*(1.0f/FF));
        const float rs = rsqrtf(var + 1e-5f);
        const float y0 = gelu_exact(fmaf((a.x-mean)*rs, g1v.x, b1v.x));
        const float y1 = gelu_exact(fmaf((a.y-mean)*rs, g1v.y, b1v.y));
        const float y2 = gelu_exact(fmaf((a.z-mean)*rs, g1v.z, b1v.z));
        const float y3 = gelu_exact(fmaf((a.w-mean)*rs, g1v.w, b1v.w));
        *(uint2*)&ytile[r][f0] = make_uint2(pack2bf(y0,y1), pack2bf(y2,y3));
    }

    __syncthreads();

    // ---- Phase 2: MFMA GEMM. Wave owns 32 rows x cols [wave*64, wave*64+64).
    const int wc = wave*64;
    f32x4 acc[2][4];
    #pragma unroll
    for(int mf=0;mf<2;++mf)
        #pragma unroll
        for(int nf=0;nf<4;++nf)
            acc[mf][nf] = (f32x4){0.f,0.f,0.f,0.f};

    #pragma unroll
    for(int kc=0;kc<8;++kc){
        short8 bfv[4];
        #pragma unroll
        for(int nf=0;nf<4;++nf)
            bfv[nf] = *(const short8*)&wimgL[(size_t)kc*10240 + (wc+nf*16+l15)*40 + qq*8];
        short8 af[2];
        #pragma unroll
        for(int mf=0;mf<2;++mf)
            af[mf] = *(const short8*)&ytile[mf*16+l15][kc*32 + qq*8];
        #pragma unroll
        for(int nf=0;nf<4;++nf)
            #pragma unroll
            for(int mf=0;mf<2;++mf)
                acc[mf][nf] = __builtin_amdgcn_mfma_f32_16x16x32_bf16(af[mf], bfv[nf], acc[mf][nf], 0,0,0);
    }

    // ---- Phase 3: +b11, LN2 (cross-wave), gelu, residual from hstash, store bf16.
    float b11c[4], g2c[4], b2c[4];
    #pragma unroll
    for(int nf=0;nf<4;++nf){
        const int col = wc + nf*16 + l15;
        b11c[nf]=b11[col]; g2c[nf]=g2[col]; b2c[nf]=b2[col];
    }
    #pragma unroll
    for(int mf=0;mf<2;++mf){
        #pragma unroll
        for(int rg=0;rg<4;++rg){
            float s=0.f, sq=0.f;
            #pragma unroll
            for(int nf=0;nf<4;++nf){
                const float v = acc[mf][nf][rg] + b11c[nf];
                s += v; sq = fmaf(v,v,sq);
            }
            #pragma unroll
            for(int o=1;o<16;o<<=1){ s += __shfl_xor(s,o,64); sq += __shfl_xor(sq,o,64); }
            if(l15==0){
                const int row = mf*16 + qq*4 + rg;
                redS[row][wave]=s; redQ[row][wave]=sq;
            }
        }
    }
    __syncthreads();
    if(tid < 32){
        const float s  = redS[tid][0]+redS[tid][1]+redS[tid][2]+redS[tid][3];
        const float q2 = redQ[tid][0]+redQ[tid][1]+redQ[tid][2]+redQ[tid][3];
        const float mean = s*(1.0f/FF);
        const float var  = fmaf(-mean, mean, q2*(1.0f/FF));
        stat[tid][0]=mean; stat[tid][1]=rsqrtf(var+1e-5f);
    }
    __syncthreads();
    #pragma unroll
    for(int mf=0;mf<2;++mf){
        #pragma unroll
        for(int rg=0;rg<4;++rg){
            const int row = mf*16 + qq*4 + rg;
            const float mean = stat[row][0], rs = stat[row][1];
            const size_t gbase = (size_t)(m0+row)*FF;
            #pragma unroll
            for(int nf=0;nf<4;++nf){
                const int col = wc + nf*16 + l15;
                const float v  = acc[mf][nf][rg] + b11c[nf];
                const float yn = fmaf((v-mean)*rs, g2c[nf], b2c[nf]);
                const float res = bf2f(*reinterpret_cast<const unsigned short*>(&hstash[row][col]));
                hbout[gbase+col] = __float2bfloat16(res + gelu_exact(yn));
            }
        }
    }
}

// P[m][0..28] = ((h[m]*mask) @ w_proj + b_proj) * mask  (stride 32) — MFMA, bf16 h in.
__global__ __launch_bounds__(256,4) void proj_kernel(
    const __hip_bfloat16* __restrict__ hbin, const float* __restrict__ mask,
    const __hip_bfloat16* __restrict__ wpimg, const float* __restrict__ bproj,
    float* __restrict__ P)
{
    __shared__ __hip_bfloat16 ytile[64][264];
    const int tid = threadIdx.x;
    const int wave = tid>>6, lane = tid&63;
    const int l15 = lane&15, qq = lane>>4;
    const int m0 = blockIdx.x*64;
    const int f0 = lane*4;

    #pragma unroll 4
    for(int rr=0; rr<16; ++rr){
        const int r = wave*16+rr;
        const int m = m0+r;
        const float mk = mask[m];
        const float4 hc = unpack4(*(const uint2*)&hbin[(size_t)m*FF + f0]);
        *(uint2*)&ytile[r][f0] = make_uint2(pack2bf(hc.x*mk, hc.y*mk), pack2bf(hc.z*mk, hc.w*mk));
    }
    __syncthreads();

    const int rh = (wave&1)*32, wc2 = (wave>>1)*16;
    f32x4 acc[2];
    acc[0] = (f32x4){0.f,0.f,0.f,0.f};
    acc[1] = (f32x4){0.f,0.f,0.f,0.f};
    #pragma unroll
    for(int kc=0;kc<8;++kc){
        const short8 bfv = *(const short8*)&wpimg[(size_t)kc*1280 + (wc2+l15)*40 + qq*8];
        #pragma unroll
        for(int mf=0;mf<2;++mf){
            const short8 af = *(const short8*)&ytile[rh+mf*16+l15][kc*32 + qq*8];
            acc[mf] = __builtin_amdgcn_mfma_f32_16x16x32_bf16(af, bfv, acc[mf], 0,0,0);
        }
    }
    const int col = wc2 + l15;
    const float bp = (col<PROJN)? bproj[col] : 0.0f;
    #pragma unroll
    for(int mf=0;mf<2;++mf){
        #pragma unroll
        for(int rg=0;rg<4;++rg){
            const int row = rh + mf*16 + qq*4 + rg;
            const float mk = mask[m0+row];
            P[(size_t)(m0+row)*32 + col] = (acc[mf][rg] + bp)*mk;
        }
    }
}

// Rational-quadratic spline per (b,t); writes xo and block-reduced logdet
__global__ __launch_bounds__(256) void spline_kernel(
    const float* __restrict__ P, const float* __restrict__ x,
    const float* __restrict__ mask, float* __restrict__ out,
    float* __restrict__ logdet)
{
    const int tid = threadIdx.x;
    const int m = blockIdx.x*256 + tid;
    float p[32];
    #pragma unroll
    for(int j=0;j<8;++j) ((float4*)p)[j] = ((const float4*)P)[(size_t)m*8+j];
    const float x0 = x[(size_t)m*2];
    const float x1 = x[(size_t)m*2+1];
    const float mk = mask[m];
    const float sc = 0.0625f;

    float cw[11], ch[11], d[11];
    {
        float mx=-1e30f;
        #pragma unroll
        for(int j=0;j<10;++j) mx = fmaxf(mx, p[j]);
        float e[10]; float se=0.f;
        #pragma unroll
        for(int j=0;j<10;++j){ e[j]=__expf((p[j]-mx)*sc); se+=e[j]; }
        const float inv = __fdividef(1.0f, se);
        float cum=0.f;
        cw[0]=-TBF;
        #pragma unroll
        for(int j=0;j<10;++j){ cum += fmaf(0.99f, e[j]*inv, 0.001f); cw[j+1]=fmaf(2.0f*TBF,cum,-TBF); }
        cw[10]=TBF;
    }
    {
        float mx=-1e30f;
        #pragma unroll
        for(int j=0;j<10;++j) mx = fmaxf(mx, p[10+j]);
        float e[10]; float se=0.f;
        #pragma unroll
        for(int j=0;j<10;++j){ e[j]=__expf((p[10+j]-mx)*sc); se+=e[j]; }
        const float inv = __fdividef(1.0f, se);
        float cum=0.f;
        ch[0]=-TBF;
        #pragma unroll
        for(int j=0;j<10;++j){ cum += fmaf(0.99f, e[j]*inv, 0.001f); ch[j+1]=fmaf(2.0f*TBF,cum,-TBF); }
        ch[10]=TBF;
    }
    d[0]=1.0f; d[10]=1.0f;
    #pragma unroll
    for(int k=1;k<10;++k) d[k] = 0.001f + softplusf_(p[19+k]);

    const bool inside = (x1>=-TBF)&&(x1<=TBF);
    const float xc = fminf(fmaxf(x1,-TBF),TBF);

    float icw=cw[0], ibw=cw[1]-cw[0], ich=ch[0], ibh=ch[1]-ch[0], dk=d[0], dk1=d[1];
    #pragma unroll
    for(int j=1;j<10;++j){
        const bool sel = (xc>=cw[j]);
        icw = sel? cw[j]      : icw;
        ibw = sel? cw[j+1]-cw[j] : ibw;
        ich = sel? ch[j]      : ich;
        ibh = sel? ch[j+1]-ch[j] : ibh;
        dk  = sel? d[j]       : dk;
        dk1 = sel? d[j+1]     : dk1;
    }

    const float delta = __fdividef(ibh, ibw);
    const float th = __fdividef(xc-icw, ibw);
    const float th1m = th*(1.0f-th);
    const float denom = fmaf(fmaf(-2.0f,delta,dk+dk1), th1m, delta);
    const float num = ibh*fmaf(delta*th, th, dk*th1m);
    const float yv = ich + __fdividef(num, denom);
    const float omt = 1.0f-th;
    const float dnum = delta*delta*(dk1*th*th + 2.0f*delta*th1m + dk*omt*omt);
    const float lad = __logf(dnum) - 2.0f*__logf(denom);
    const float y1 = inside? yv : x1;
    const float lv = inside? lad : 0.0f;

    out[(size_t)m*2]   = x0*mk;
    out[(size_t)m*2+1] = y1*mk;

    __shared__ float red[256];
    red[tid]=lv*mk;
    __syncthreads();
    #pragma unroll
    for(int s=128;s>0;s>>=1){ if(tid<s) red[tid]+=red[tid+s]; __syncthreads(); }
    if(tid==0) atomicAdd(&logdet[blockIdx.x>>5], red[0]);
}

extern "C" void kernel_launch(void* const* d_in, const int* in_sizes, int n_in,
                              void* d_out, int out_size, void* d_ws, size_t ws_size,
                              hipStream_t stream)
{
    const float* x      = (const float*)d_in[0];
    const float* mask   = (const float*)d_in[1];
    const float* w_pre  = (const float*)d_in[2];
    const float* b_pre  = (const float*)d_in[3];
    const float* dw_k   = (const float*)d_in[4];
    const float* dw_b   = (const float*)d_in[5];
    const float* w11    = (const float*)d_in[6];
    const float* b11    = (const float*)d_in[7];
    const float* ln1g   = (const float*)d_in[8];
    const float* ln1b   = (const float*)d_in[9];
    const float* ln2g   = (const float*)d_in[10];
    const float* ln2b   = (const float*)d_in[11];
    const float* w_proj = (const float*)d_in[12];
    const float* b_proj = (const float*)d_in[13];

    const size_t hbytes_f32 = (size_t)MM*FF*4;       // legacy layout anchor (128 MiB)
    __hip_bfloat16* h0 = (__hip_bfloat16*)d_ws;                  // 64 MiB
    __hip_bfloat16* h1 = h0 + (size_t)MM*FF;                     // 64 MiB
    // P (f32, stride 32 = 16 MiB) overlays h0's region — h0 is dead after layer 2.
    float* P = (float*)d_ws;
    float* outp   = (float*)d_out;
    float* logdet = outp + (size_t)MM*2;

    __hip_bfloat16* wimg;
    if(ws_size >= 2*hbytes_f32 + 3*163840 + 20480)
        wimg = (__hip_bfloat16*)((char*)d_ws + 2*hbytes_f32);
    else
        wimg = (__hip_bfloat16*)d_out;
    __hip_bfloat16* wpimg = wimg + (size_t)3*81920;

    wprep_kernel<<<32, 256, 0, stream>>>(w11, w_proj, wimg, wpimg);

    // layer 0 fuses the rank-1 pre-expansion; ping-pong bf16 h. dil = 1, 3, 9.
    layer_kernel<<<MM/32, 256, 0, stream>>>(
        (const __hip_bfloat16*)nullptr, h1, x, w_pre, b_pre, mask,
        dw_k, dw_b, ln1g, ln1b, wimg, b11, ln2g, ln2b, 1, 1);
    layer_kernel<<<MM/32, 256, 0, stream>>>(
        h1, h0, x, w_pre, b_pre, mask,
        dw_k + (size_t)3*FF, dw_b + (size_t)FF,
        ln1g + (size_t)FF, ln1b + (size_t)FF,
        wimg + (size_t)81920, b11 + (size_t)FF,
        ln2g + (size_t)FF, ln2b + (size_t)FF, 3, 0);
    layer_kernel<<<MM/32, 256, 0, stream>>>(
        h0, h1, x, w_pre, b_pre, mask,
        dw_k + (size_t)6*FF, dw_b + (size_t)2*FF,
        ln1g + (size_t)2*FF, ln1b + (size_t)2*FF,
        wimg + (size_t)2*81920, b11 + (size_t)2*FF,
        ln2g + (size_t)2*FF, ln2b + (size_t)2*FF, 9, 0);

    proj_kernel<<<MM/64, 256, 0, stream>>>(h1, mask, wpimg, b_proj, P);

    hipMemsetAsync(logdet, 0, BB*sizeof(float), stream);
    spline_kernel<<<MM/256, 256, 0, stream>>>(P, x, mask, outp, logdet);
}

// Round 9
// 327.461 us; speedup vs baseline: 9.2649x; 1.0826x over previous
//
#include <hip/hip_runtime.h>
#include <hip/hip_bf16.h>
#include <cmath>

#define BB 16
#define TT 8192
#define MM (BB*TT)
#define FF 256
#define TBF 5.0f
#define PROJN 29

typedef __attribute__((ext_vector_type(8))) short short8;
typedef __attribute__((ext_vector_type(4))) float f32x4;

// tanh-form gelu: x*sigmoid(x*(c1 + c2*x^2)); max abs err vs exact ~3e-4,
// below the bf16 rounding noise already present in the h chain.
__device__ __forceinline__ float gelu_fast(float x){
    const float x2 = x*x;
    const float v  = x*fmaf(0.07135481627f, x2, 1.595769122f);
    const float e  = __expf(-v);
    return x*__builtin_amdgcn_rcpf(1.0f + e);
}
__device__ __forceinline__ float softplusf_(float v){
    return fmaxf(v,0.0f) + log1pf(__expf(-fabsf(v)));
}
__device__ __forceinline__ unsigned pack2bf(float a, float b){
    __hip_bfloat16 ha = __float2bfloat16(a);
    __hip_bfloat16 hb = __float2bfloat16(b);
    const unsigned ua = *reinterpret_cast<const unsigned short*>(&ha);
    const unsigned ub = *reinterpret_cast<const unsigned short*>(&hb);
    return ua | (ub<<16);
}
__device__ __forceinline__ float bf2f(unsigned short u){
    unsigned v = ((unsigned)u)<<16;
    return *reinterpret_cast<float*>(&v);
}
__device__ __forceinline__ float4 unpack4(uint2 q){
    float4 f;
    f.x = bf2f((unsigned short)(q.x&0xffff)); f.y = bf2f((unsigned short)(q.x>>16));
    f.z = bf2f((unsigned short)(q.y&0xffff)); f.w = bf2f((unsigned short)(q.y>>16));
    return f;
}

// Layer images: wimg[layer][kc][n][40] bf16, [n][kp] = w11[kc*32+kp][n] (kp<32; pad 0).
// Proj image (blocks 24..31): wpimg[kc][n 0..31][40].
__global__ __launch_bounds__(256) void wprep_kernel(
    const float* __restrict__ w11, const float* __restrict__ wproj,
    __hip_bfloat16* __restrict__ wimg, __hip_bfloat16* __restrict__ wpimg)
{
    if(blockIdx.x < 24){
        const int layer = blockIdx.x>>3, kc = blockIdx.x&7;
        const float* __restrict__ w = w11 + (size_t)layer*FF*FF;
        __hip_bfloat16* __restrict__ o = wimg + (size_t)layer*81920 + kc*10240;
        for(int i=threadIdx.x; i<10240; i+=256){
            const int n = i/40, kp = i - n*40;
            const float v = (kp<32) ? w[(size_t)(kc*32+kp)*FF + n] : 0.0f;
            o[i] = __float2bfloat16(v);
        }
    } else {
        const int kc = blockIdx.x - 24;
        __hip_bfloat16* __restrict__ o = wpimg + (size_t)kc*1280;
        for(int i=threadIdx.x; i<1280; i+=256){
            const int n = i/40, kp = i - n*40;
            const float v = (kp<32 && n<PROJN) ? wproj[(size_t)(kc*32+kp)*PROJN + n] : 0.0f;
            o[i] = __float2bfloat16(v);
        }
    }
}

// One layer, 32 rows x 256 cols per block, 4 waves, bf16 MFMA 16x16x32.
__global__ __launch_bounds__(256,4) void layer_kernel(
    const __hip_bfloat16* __restrict__ hbin, __hip_bfloat16* __restrict__ hbout,
    const float* __restrict__ xsrc,
    const float* __restrict__ w_pre, const float* __restrict__ b_pre,
    const float* __restrict__ mask,
    const float* __restrict__ dwk, const float* __restrict__ dwb,
    const float* __restrict__ g1, const float* __restrict__ b1,
    const __hip_bfloat16* __restrict__ wimgL, const float* __restrict__ b11,
    const float* __restrict__ g2, const float* __restrict__ b2,
    const int dil, const int pre_mode)
{
    __shared__ __hip_bfloat16 ytile[32][260];   // stride 260: row offset 2 banks
    __shared__ __hip_bfloat16 hstash[32][260];
    __shared__ float redS[32][4];
    __shared__ float redQ[32][4];
    __shared__ float stat[32][2];

    const int tid  = threadIdx.x;
    const int wave = tid>>6, lane = tid&63;
    const int l15  = lane&15, qq = lane>>4;

    int bid = blockIdx.x;                        // XCD swizzle (4096%8==0)
    bid = (bid&7)*((int)gridDim.x>>3) + (bid>>3);
    const int m0 = bid*32;
    const int b  = m0/TT;
    const int t0 = m0 - b*TT;
    const float* __restrict__ mrow = mask + (size_t)b*TT;

    // ---- Phase 1: conv + LN1 + gelu -> ytile; stash center h -> hstash.
    const int f0 = lane*4;
    const float4 k0 = *(const float4*)&dwk[f0];
    const float4 k1 = *(const float4*)&dwk[FF+f0];
    const float4 k2 = *(const float4*)&dwk[2*FF+f0];
    const float4 cb = *(const float4*)&dwb[f0];
    const float4 g1v= *(const float4*)&g1[f0];
    const float4 b1v= *(const float4*)&b1[f0];
    float4 wp4, bp4;
    if(pre_mode){ wp4 = *(const float4*)&w_pre[f0]; bp4 = *(const float4*)&b_pre[f0]; }

    #pragma unroll 4
    for(int rr=0; rr<8; ++rr){
        const int r = wave*8+rr;
        const int m = m0+r, t = t0+r;
        const int okl = (t>=dil)   ? 1 : 0;
        const int okr = (t+dil<TT) ? 1 : 0;
        const int ml  = m - dil*okl;
        const int mr  = m + dil*okr;
        const float mkc = mrow[t];
        const float mkl = mrow[t - dil*okl] * (float)okl;
        const float mkr = mrow[t + dil*okr] * (float)okr;
        float4 hc, hl, hr;
        uint2 hcraw;
        if(pre_mode){
            const float xc_ = xsrc[(size_t)m *2];
            const float xl_ = xsrc[(size_t)ml*2];
            const float xr_ = xsrc[(size_t)mr*2];
            hc.x=fmaf(xc_,wp4.x,bp4.x); hc.y=fmaf(xc_,wp4.y,bp4.y);
            hc.z=fmaf(xc_,wp4.z,bp4.z); hc.w=fmaf(xc_,wp4.w,bp4.w);
            hl.x=fmaf(xl_,wp4.x,bp4.x); hl.y=fmaf(xl_,wp4.y,bp4.y);
            hl.z=fmaf(xl_,wp4.z,bp4.z); hl.w=fmaf(xl_,wp4.w,bp4.w);
            hr.x=fmaf(xr_,wp4.x,bp4.x); hr.y=fmaf(xr_,wp4.y,bp4.y);
            hr.z=fmaf(xr_,wp4.z,bp4.z); hr.w=fmaf(xr_,wp4.w,bp4.w);
            hcraw = make_uint2(pack2bf(hc.x,hc.y), pack2bf(hc.z,hc.w));
        } else {
            hcraw          = *(const uint2*)&hbin[(size_t)m *FF + f0];
            const uint2 ql = *(const uint2*)&hbin[(size_t)ml*FF + f0];
            const uint2 qr = *(const uint2*)&hbin[(size_t)mr*FF + f0];
            hc = unpack4(hcraw); hl = unpack4(ql); hr = unpack4(qr);
        }
        *(uint2*)&hstash[r][f0] = hcraw;
        float4 a;
        a.x = fmaf(hc.x*mkc, k1.x, cb.x);
        a.y = fmaf(hc.y*mkc, k1.y, cb.y);
        a.z = fmaf(hc.z*mkc, k1.z, cb.z);
        a.w = fmaf(hc.w*mkc, k1.w, cb.w);
        a.x = fmaf(hl.x*mkl, k0.x, a.x);
        a.y = fmaf(hl.y*mkl, k0.y, a.y);
        a.z = fmaf(hl.z*mkl, k0.z, a.z);
        a.w = fmaf(hl.w*mkl, k0.w, a.w);
        a.x = fmaf(hr.x*mkr, k2.x, a.x);
        a.y = fmaf(hr.y*mkr, k2.y, a.y);
        a.z = fmaf(hr.z*mkr, k2.z, a.z);
        a.w = fmaf(hr.w*mkr, k2.w, a.w);
        float s  = a.x+a.y+a.z+a.w;
        float sq = fmaf(a.x,a.x, fmaf(a.y,a.y, fmaf(a.z,a.z, a.w*a.w)));
        #pragma unroll
        for(int o=32;o>0;o>>=1){
            s  += __shfl_xor(s,o,64);
            sq += __shfl_xor(sq,o,64);
        }
        const float mean = s*(1.0f/FF);
        const float var  = fmaf(-mean, mean, sq*(1.0f/FF));
        const float rs = rsqrtf(var + 1e-5f);
        const float y0 = gelu_fast(fmaf((a.x-mean)*rs, g1v.x, b1v.x));
        const float y1 = gelu_fast(fmaf((a.y-mean)*rs, g1v.y, b1v.y));
        const float y2 = gelu_fast(fmaf((a.z-mean)*rs, g1v.z, b1v.z));
        const float y3 = gelu_fast(fmaf((a.w-mean)*rs, g1v.w, b1v.w));
        *(uint2*)&ytile[r][f0] = make_uint2(pack2bf(y0,y1), pack2bf(y2,y3));
    }

    __syncthreads();

    // ---- Phase 2: MFMA GEMM. Wave owns 32 rows x cols [wave*64, wave*64+64).
    const int wc = wave*64;
    f32x4 acc[2][4];
    #pragma unroll
    for(int mf=0;mf<2;++mf)
        #pragma unroll
        for(int nf=0;nf<4;++nf)
            acc[mf][nf] = (f32x4){0.f,0.f,0.f,0.f};

    #pragma unroll
    for(int kc=0;kc<8;++kc){
        short8 bfv[4];
        #pragma unroll
        for(int nf=0;nf<4;++nf)
            bfv[nf] = *(const short8*)&wimgL[(size_t)kc*10240 + (wc+nf*16+l15)*40 + qq*8];
        short8 af[2];
        #pragma unroll
        for(int mf=0;mf<2;++mf)
            af[mf] = *(const short8*)&ytile[mf*16+l15][kc*32 + qq*8];
        #pragma unroll
        for(int nf=0;nf<4;++nf)
            #pragma unroll
            for(int mf=0;mf<2;++mf)
                acc[mf][nf] = __builtin_amdgcn_mfma_f32_16x16x32_bf16(af[mf], bfv[nf], acc[mf][nf], 0,0,0);
    }

    // ---- Phase 3: +b11, LN2 (cross-wave), gelu, residual from hstash, store bf16.
    float b11c[4], g2c[4], b2c[4];
    #pragma unroll
    for(int nf=0;nf<4;++nf){
        const int col = wc + nf*16 + l15;
        b11c[nf]=b11[col]; g2c[nf]=g2[col]; b2c[nf]=b2[col];
    }
    #pragma unroll
    for(int mf=0;mf<2;++mf){
        #pragma unroll
        for(int rg=0;rg<4;++rg){
            float s=0.f, sq=0.f;
            #pragma unroll
            for(int nf=0;nf<4;++nf){
                const float v = acc[mf][nf][rg] + b11c[nf];
                s += v; sq = fmaf(v,v,sq);
            }
            #pragma unroll
            for(int o=1;o<16;o<<=1){ s += __shfl_xor(s,o,64); sq += __shfl_xor(sq,o,64); }
            if(l15==0){
                const int row = mf*16 + qq*4 + rg;
                redS[row][wave]=s; redQ[row][wave]=sq;
            }
        }
    }
    __syncthreads();
    if(tid < 32){
        const float s  = redS[tid][0]+redS[tid][1]+redS[tid][2]+redS[tid][3];
        const float q2 = redQ[tid][0]+redQ[tid][1]+redQ[tid][2]+redQ[tid][3];
        const float mean = s*(1.0f/FF);
        const float var  = fmaf(-mean, mean, q2*(1.0f/FF));
        stat[tid][0]=mean; stat[tid][1]=rsqrtf(var+1e-5f);
    }
    __syncthreads();
    #pragma unroll
    for(int mf=0;mf<2;++mf){
        #pragma unroll
        for(int rg=0;rg<4;++rg){
            const int row = mf*16 + qq*4 + rg;
            const float mean = stat[row][0], rs = stat[row][1];
            const size_t gbase = (size_t)(m0+row)*FF;
            #pragma unroll
            for(int nf=0;nf<4;++nf){
                const int col = wc + nf*16 + l15;
                const float v  = acc[mf][nf][rg] + b11c[nf];
                const float yn = fmaf((v-mean)*rs, g2c[nf], b2c[nf]);
                const float res = bf2f(*reinterpret_cast<const unsigned short*>(&hstash[row][col]));
                hbout[gbase+col] = __float2bfloat16(res + gelu_fast(yn));
            }
        }
    }
}

// ---------- Fused proj + spline: 256 rows/block ----------
__global__ __launch_bounds__(256,2) void projspline_kernel(
    const __hip_bfloat16* __restrict__ hbin, const float* __restrict__ mask,
    const __hip_bfloat16* __restrict__ wpimg, const float* __restrict__ bproj,
    const float* __restrict__ x, float* __restrict__ out,
    float* __restrict__ logdet)
{
    __shared__ __hip_bfloat16 ytile[64][260];
    __shared__ float Pl[256][37];
    __shared__ float red[256];

    const int tid = threadIdx.x;
    const int wave = tid>>6, lane = tid&63;
    const int l15 = lane&15, qq = lane>>4;
    const int m0 = blockIdx.x*256;
    const int f0 = lane*4;

    const int col = (wave>>1)*16 + l15;
    const float bp = (col<PROJN)? bproj[col] : 0.0f;

    for(int ch=0; ch<4; ++ch){
        const int mc = m0 + ch*64;
        #pragma unroll 4
        for(int rr=0; rr<16; ++rr){
            const int r = wave*16+rr;
            const int m = mc+r;
            const float mk = mask[m];
            const float4 hc = unpack4(*(const uint2*)&hbin[(size_t)m*FF + f0]);
            *(uint2*)&ytile[r][f0] = make_uint2(pack2bf(hc.x*mk, hc.y*mk), pack2bf(hc.z*mk, hc.w*mk));
        }
        __syncthreads();

        const int rh = (wave&1)*32, wc2 = (wave>>1)*16;
        f32x4 acc[2];
        acc[0] = (f32x4){0.f,0.f,0.f,0.f};
        acc[1] = (f32x4){0.f,0.f,0.f,0.f};
        #pragma unroll
        for(int kc=0;kc<8;++kc){
            const short8 bfv = *(const short8*)&wpimg[(size_t)kc*1280 + (wc2+l15)*40 + qq*8];
            #pragma unroll
            for(int mf=0;mf<2;++mf){
                const short8 af = *(const short8*)&ytile[rh+mf*16+l15][kc*32 + qq*8];
                acc[mf] = __builtin_amdgcn_mfma_f32_16x16x32_bf16(af, bfv, acc[mf], 0,0,0);
            }
        }
        #pragma unroll
        for(int mf=0;mf<2;++mf){
            #pragma unroll
            for(int rg=0;rg<4;++rg){
                const int row = rh + mf*16 + qq*4 + rg;
                const float mk = mask[mc+row];
                Pl[ch*64+row][col] = (acc[mf][rg] + bp)*mk;
            }
        }
        __syncthreads();   // Pl written; ytile reusable next chunk
    }

    // ---- spline: one row per thread
    const int m = m0 + tid;
    float p[29];
    #pragma unroll
    for(int j=0;j<29;++j) p[j] = Pl[tid][j];
    const float x0 = x[(size_t)m*2];
    const float x1 = x[(size_t)m*2+1];
    const float mk = mask[m];
    const float sc = 0.0625f;

    float cw[11], ch_[11], d[11];
    {
        float mx=-1e30f;
        #pragma unroll
        for(int j=0;j<10;++j) mx = fmaxf(mx, p[j]);
        float e[10]; float se=0.f;
        #pragma unroll
        for(int j=0;j<10;++j){ e[j]=__expf((p[j]-mx)*sc); se+=e[j]; }
        const float inv = __builtin_amdgcn_rcpf(se);
        float cum=0.f;
        cw[0]=-TBF;
        #pragma unroll
        for(int j=0;j<10;++j){ cum += fmaf(0.99f, e[j]*inv, 0.001f); cw[j+1]=fmaf(2.0f*TBF,cum,-TBF); }
        cw[10]=TBF;
    }
    {
        float mx=-1e30f;
        #pragma unroll
        for(int j=0;j<10;++j) mx = fmaxf(mx, p[10+j]);
        float e[10]; float se=0.f;
        #pragma unroll
        for(int j=0;j<10;++j){ e[j]=__expf((p[10+j]-mx)*sc); se+=e[j]; }
        const float inv = __builtin_amdgcn_rcpf(se);
        float cum=0.f;
        ch_[0]=-TBF;
        #pragma unroll
        for(int j=0;j<10;++j){ cum += fmaf(0.99f, e[j]*inv, 0.001f); ch_[j+1]=fmaf(2.0f*TBF,cum,-TBF); }
        ch_[10]=TBF;
    }
    d[0]=1.0f; d[10]=1.0f;
    #pragma unroll
    for(int k=1;k<10;++k) d[k] = 0.001f + softplusf_(p[19+k]);

    const bool inside = (x1>=-TBF)&&(x1<=TBF);
    const float xc = fminf(fmaxf(x1,-TBF),TBF);

    float icw=cw[0], ibw=cw[1]-cw[0], ich=ch_[0], ibh=ch_[1]-ch_[0], dk=d[0], dk1=d[1];
    #pragma unroll
    for(int j=1;j<10;++j){
        const bool sel = (xc>=cw[j]);
        icw = sel? cw[j]        : icw;
        ibw = sel? cw[j+1]-cw[j]: ibw;
        ich = sel? ch_[j]       : ich;
        ibh = sel? ch_[j+1]-ch_[j]: ibh;
        dk  = sel? d[j]         : dk;
        dk1 = sel? d[j+1]       : dk1;
    }

    const float delta = __fdividef(ibh, ibw);
    const float th = __fdividef(xc-icw, ibw);
    const float th1m = th*(1.0f-th);
    const float denom = fmaf(fmaf(-2.0f,delta,dk+dk1), th1m, delta);
    const float num = ibh*fmaf(delta*th, th, dk*th1m);
    const float rcd = __builtin_amdgcn_rcpf(denom);
    const float yv = ich + num*rcd;
    const float omt = 1.0f-th;
    const float dnum = delta*delta*(dk1*th*th + 2.0f*delta*th1m + dk*omt*omt);
    const float lad = __logf(dnum*rcd*rcd);
    const float y1 = inside? yv : x1;
    const float lv = inside? lad : 0.0f;

    out[(size_t)m*2]   = x0*mk;
    out[(size_t)m*2+1] = y1*mk;

    red[tid]=lv*mk;
    __syncthreads();
    #pragma unroll
    for(int s=128;s>0;s>>=1){ if(tid<s) red[tid]+=red[tid+s]; __syncthreads(); }
    if(tid==0) atomicAdd(&logdet[blockIdx.x>>5], red[0]);   // 32 blocks / batch
}

// ---------- Fallback pair (used only if ws can't host wimg) ----------
__global__ __launch_bounds__(256,4) void proj_kernel(
    const __hip_bfloat16* __restrict__ hbin, const float* __restrict__ mask,
    const __hip_bfloat16* __restrict__ wpimg, const float* __restrict__ bproj,
    float* __restrict__ P)
{
    __shared__ __hip_bfloat16 ytile[64][260];
    const int tid = threadIdx.x;
    const int wave = tid>>6, lane = tid&63;
    const int l15 = lane&15, qq = lane>>4;
    const int m0 = blockIdx.x*64;
    const int f0 = lane*4;

    #pragma unroll 4
    for(int rr=0; rr<16; ++rr){
        const int r = wave*16+rr;
        const int m = m0+r;
        const float mk = mask[m];
        const float4 hc = unpack4(*(const uint2*)&hbin[(size_t)m*FF + f0]);
        *(uint2*)&ytile[r][f0] = make_uint2(pack2bf(hc.x*mk, hc.y*mk), pack2bf(hc.z*mk, hc.w*mk));
    }
    __syncthreads();

    const int rh = (wave&1)*32, wc2 = (wave>>1)*16;
    f32x4 acc[2];
    acc[0] = (f32x4){0.f,0.f,0.f,0.f};
    acc[1] = (f32x4){0.f,0.f,0.f,0.f};
    #pragma unroll
    for(int kc=0;kc<8;++kc){
        const short8 bfv = *(const short8*)&wpimg[(size_t)kc*1280 + (wc2+l15)*40 + qq*8];
        #pragma unroll
        for(int mf=0;mf<2;++mf){
            const short8 af = *(const short8*)&ytile[rh+mf*16+l15][kc*32 + qq*8];
            acc[mf] = __builtin_amdgcn_mfma_f32_16x16x32_bf16(af, bfv, acc[mf], 0,0,0);
        }
    }
    const int col = wc2 + l15;
    const float bp = (col<PROJN)? bproj[col] : 0.0f;
    #pragma unroll
    for(int mf=0;mf<2;++mf){
        #pragma unroll
        for(int rg=0;rg<4;++rg){
            const int row = rh + mf*16 + qq*4 + rg;
            const float mk = mask[m0+row];
            P[(size_t)(m0+row)*32 + col] = (acc[mf][rg] + bp)*mk;
        }
    }
}

__global__ __launch_bounds__(256) void spline_kernel(
    const float* __restrict__ P, const float* __restrict__ x,
    const float* __restrict__ mask, float* __restrict__ out,
    float* __restrict__ logdet)
{
    const int tid = threadIdx.x;
    const int m = blockIdx.x*256 + tid;
    float p[32];
    #pragma unroll
    for(int j=0;j<8;++j) ((float4*)p)[j] = ((const float4*)P)[(size_t)m*8+j];
    const float x0 = x[(size_t)m*2];
    const float x1 = x[(size_t)m*2+1];
    const float mk = mask[m];
    const float sc = 0.0625f;

    float cw[11], ch_[11], d[11];
    {
        float mx=-1e30f;
        #pragma unroll
        for(int j=0;j<10;++j) mx = fmaxf(mx, p[j]);
        float e[10]; float se=0.f;
        #pragma unroll
        for(int j=0;j<10;++j){ e[j]=__expf((p[j]-mx)*sc); se+=e[j]; }
        const float inv = __builtin_amdgcn_rcpf(se);
        float cum=0.f;
        cw[0]=-TBF;
        #pragma unroll
        for(int j=0;j<10;++j){ cum += fmaf(0.99f, e[j]*inv, 0.001f); cw[j+1]=fmaf(2.0f*TBF,cum,-TBF); }
        cw[10]=TBF;
    }
    {
        float mx=-1e30f;
        #pragma unroll
        for(int j=0;j<10;++j) mx = fmaxf(mx, p[10+j]);
        float e[10]; float se=0.f;
        #pragma unroll
        for(int j=0;j<10;++j){ e[j]=__expf((p[10+j]-mx)*sc); se+=e[j]; }
        const float inv = __builtin_amdgcn_rcpf(se);
        float cum=0.f;
        ch_[0]=-TBF;
        #pragma unroll
        for(int j=0;j<10;++j){ cum += fmaf(0.99f, e[j]*inv, 0.001f); ch_[j+1]=fmaf(2.0f*TBF,cum,-TBF); }
        ch_[10]=TBF;
    }
    d[0]=1.0f; d[10]=1.0f;
    #pragma unroll
    for(int k=1;k<10;++k) d[k] = 0.001f + softplusf_(p[19+k]);

    const bool inside = (x1>=-TBF)&&(x1<=TBF);
    const float xc = fminf(fmaxf(x1,-TBF),TBF);

    float icw=cw[0], ibw=cw[1]-cw[0], ich=ch_[0], ibh=ch_[1]-ch_[0], dk=d[0], dk1=d[1];
    #pragma unroll
    for(int j=1;j<10;++j){
        const bool sel = (xc>=cw[j]);
        icw = sel? cw[j]        : icw;
        ibw = sel? cw[j+1]-cw[j]: ibw;
        ich = sel? ch_[j]       : ich;
        ibh = sel? ch_[j+1]-ch_[j]: ibh;
        dk  = sel? d[j]         : dk;
        dk1 = sel? d[j+1]       : dk1;
    }

    const float delta = __fdividef(ibh, ibw);
    const float th = __fdividef(xc-icw, ibw);
    const float th1m = th*(1.0f-th);
    const float denom = fmaf(fmaf(-2.0f,delta,dk+dk1), th1m, delta);
    const float num = ibh*fmaf(delta*th, th, dk*th1m);
    const float rcd = __builtin_amdgcn_rcpf(denom);
    const float yv = ich + num*rcd;
    const float omt = 1.0f-th;
    const float dnum = delta*delta*(dk1*th*th + 2.0f*delta*th1m + dk*omt*omt);
    const float lad = __logf(dnum*rcd*rcd);
    const float y1 = inside? yv : x1;
    const float lv = inside? lad : 0.0f;

    out[(size_t)m*2]   = x0*mk;
    out[(size_t)m*2+1] = y1*mk;

    __shared__ float red[256];
    red[tid]=lv*mk;
    __syncthreads();
    #pragma unroll
    for(int s=128;s>0;s>>=1){ if(tid<s) red[tid]+=red[tid+s]; __syncthreads(); }
    if(tid==0) atomicAdd(&logdet[blockIdx.x>>5], red[0]);
}

extern "C" void kernel_launch(void* const* d_in, const int* in_sizes, int n_in,
                              void* d_out, int out_size, void* d_ws, size_t ws_size,
                              hipStream_t stream)
{
    const float* x      = (const float*)d_in[0];
    const float* mask   = (const float*)d_in[1];
    const float* w_pre  = (const float*)d_in[2];
    const float* b_pre  = (const float*)d_in[3];
    const float* dw_k   = (const float*)d_in[4];
    const float* dw_b   = (const float*)d_in[5];
    const float* w11    = (const float*)d_in[6];
    const float* b11    = (const float*)d_in[7];
    const float* ln1g   = (const float*)d_in[8];
    const float* ln1b   = (const float*)d_in[9];
    const float* ln2g   = (const float*)d_in[10];
    const float* ln2b   = (const float*)d_in[11];
    const float* w_proj = (const float*)d_in[12];
    const float* b_proj = (const float*)d_in[13];

    const size_t hbytes_bf16 = (size_t)MM*FF*2;        // 64 MiB each
    __hip_bfloat16* h0 = (__hip_bfloat16*)d_ws;
    __hip_bfloat16* h1 = h0 + (size_t)MM*FF;
    float* outp   = (float*)d_out;
    float* logdet = outp + (size_t)MM*2;

    // wimg/wpimg: prefer ws tail right after the two bf16 h buffers.
    const size_t wimg_bytes = (size_t)3*163840 + 20480;
    __hip_bfloat16* wimg;
    const bool ws_ok = (ws_size >= 2*hbytes_bf16 + wimg_bytes);
    if(ws_ok) wimg = (__hip_bfloat16*)((char*)d_ws + 2*hbytes_bf16);
    else      wimg = (__hip_bfloat16*)d_out;   // fallback: separate proj+spline
    __hip_bfloat16* wpimg = wimg + (size_t)3*81920;

    wprep_kernel<<<32, 256, 0, stream>>>(w11, w_proj, wimg, wpimg);

    layer_kernel<<<MM/32, 256, 0, stream>>>(
        (const __hip_bfloat16*)nullptr, h1, x, w_pre, b_pre, mask,
        dw_k, dw_b, ln1g, ln1b, wimg, b11, ln2g, ln2b, 1, 1);
    layer_kernel<<<MM/32, 256, 0, stream>>>(
        h1, h0, x, w_pre, b_pre, mask,
        dw_k + (size_t)3*FF, dw_b + (size_t)FF,
        ln1g + (size_t)FF, ln1b + (size_t)FF,
        wimg + (size_t)81920, b11 + (size_t)FF,
        ln2g + (size_t)FF, ln2b + (size_t)FF, 3, 0);
    layer_kernel<<<MM/32, 256, 0, stream>>>(
        h0, h1, x, w_pre, b_pre, mask,
        dw_k + (size_t)6*FF, dw_b + (size_t)2*FF,
        ln1g + (size_t)2*FF, ln1b + (size_t)2*FF,
        wimg + (size_t)2*81920, b11 + (size_t)2*FF,
        ln2g + (size_t)2*FF, ln2b + (size_t)2*FF, 9, 0);

    hipMemsetAsync(logdet, 0, BB*sizeof(float), stream);
    if(ws_ok){
        projspline_kernel<<<MM/256, 256, 0, stream>>>(h1, mask, wpimg, b_proj, x, outp, logdet);
    } else {
        float* P = (float*)d_ws;    // overlay h0 (dead after layer 2)
        proj_kernel<<<MM/64, 256, 0, stream>>>(h1, mask, wpimg, b_proj, P);
        spline_kernel<<<MM/256, 256, 0, stream>>>(P, x, mask, outp, logdet);
    }
}